// Round 13
// baseline (191.301 us; speedup 1.0000x reference)
//
#include <hip/hip_runtime.h>
#include <hip/hip_bf16.h>

// Problem constants (B=1)
#define T_ 8
#define H_ 64
#define W_ 64
#define C_ 64
#define HW_ (H_ * W_)          // 4096
#define THW_ (T_ * H_ * W_)    // 32768
#define KTAPS 27
#define KDIM (C_ * KTAPS)      // 1728
#define NOFF 54
#define WR_ 5                  // window rows (h-2..h+2)
#define WC_ 38                 // window cols (w0-2..w0+35)
#define WCP 40                 // padded col stride

typedef __bf16 bf16x8 __attribute__((ext_vector_type(8)));
typedef float floatx4 __attribute__((ext_vector_type(4)));

#define LGKM_BARRIER()                                        \
    do {                                                      \
        asm volatile("s_waitcnt lgkmcnt(0)" ::: "memory");    \
        __builtin_amdgcn_s_barrier();                         \
    } while (0)

// h-stripe XCD swizzle (R10-VERIFIED: FETCH 12.6->6.8MB, kept).
// grid 1024: bid = (t*16 + (h&7)*2 + wh)*8 + (h>>3)
#define DECODE_SWZ_CONV(bid, t, h, wh)                        \
    const int hi3_ = (bid) & 7;                               \
    const int rest_ = (bid) >> 3;                             \
    const int wh = rest_ & 1;                                 \
    const int h = hi3_ * 8 + ((rest_ >> 1) & 7);              \
    const int t = rest_ >> 4;

// ---------------------------------------------------------------------------
// prep + to_cl merged (unchanged).
// ---------------------------------------------------------------------------
__global__ __launch_bounds__(256) void prep_tocl_kernel(
    const float* __restrict__ x, __hip_bfloat16* __restrict__ xcl,
    const float* __restrict__ w1, const float* __restrict__ woff,
    const float* __restrict__ wd, const float* __restrict__ wr,
    __hip_bfloat16* __restrict__ w1s, __hip_bfloat16* __restrict__ woffs,
    __hip_bfloat16* __restrict__ wds, __hip_bfloat16* __restrict__ wrs) {
    __shared__ float tile[64][65];
    const int tid = threadIdx.x;

    {
        int i = blockIdx.x * 256 + tid;
        if (i < C_ * KDIM) {
            int j = i & 7, lane = (i >> 3) & 63, s = (i >> 9) & 1, g16 = (i >> 10) & 3, tap = i >> 12;
            int co = g16 * 16 + (lane & 15);
            int cin = s * 32 + (lane >> 4) * 8 + j;
            int src = (co * C_ + cin) * KTAPS + tap;
            w1s[i] = __float2bfloat16(w1[src]);
            woffs[i] = (co < NOFF) ? __float2bfloat16(woff[src]) : __float2bfloat16(0.f);
            wds[i] = __float2bfloat16(wd[src]);
        }
        if (i < C_ * C_) {
            int j = i & 7, lane = (i >> 3) & 63, s = (i >> 9) & 1, g16 = i >> 10;
            int co = g16 * 16 + (lane & 15);
            int cin = s * 32 + (lane >> 4) * 8 + j;
            wrs[i] = __float2bfloat16(wr[co * C_ + cin]);
        }
    }

    const int pos0 = blockIdx.x * 64;
    for (int i = tid; i < 4096; i += 256) {
        int ch = i >> 6, p = i & 63;
        tile[ch][p] = x[ch * THW_ + pos0 + p];
    }
    __syncthreads();
    for (int i = tid; i < 4096; i += 256) {
        int p = i >> 6, ch = i & 63;
        xcl[(pos0 + p) * C_ + ch] = __float2bfloat16(tile[ch][p]);
    }
}

// ---------------------------------------------------------------------------
// BARRIER-FREE per-wave streaming MFMA 3x3x3 conv (conv1) — R10 verbatim.
// ---------------------------------------------------------------------------
__global__ __launch_bounds__(256) void conv_stream_kernel(
    const __hip_bfloat16* __restrict__ in_cl,
    const __hip_bfloat16* __restrict__ wTs,
    const float* __restrict__ bias,
    __hip_bfloat16* __restrict__ out_cl_b16) {
    __shared__ __hip_bfloat16 ts[32 * 72];

    const int tid = threadIdx.x;
    const int wv = tid >> 6;
    const int lane = tid & 63;
    const int l15 = lane & 15;
    const int quad = lane >> 4;
    DECODE_SWZ_CONV(blockIdx.x, t, h, wh)
    const int w0 = wh * 32;
    const int pg = wv >> 1;
    const int chf = wv & 1;
    const int wpos = w0 + pg * 16 + l15;
    const int posbase = t * HW_ + h * W_;

    floatx4 acc0 = (floatx4){0.f, 0.f, 0.f, 0.f};
    floatx4 acc1 = (floatx4){0.f, 0.f, 0.f, 0.f};
    const bf16x8 z = {};
    const __hip_bfloat16* wb = wTs + chf * 2048 + lane * 8;

    const int ktlo = (t == 0) ? 1 : 0;
    const int kthi = (t == T_ - 1) ? 2 : 3;

    for (int kt = ktlo; kt < kthi; ++kt) {
        const int t_in = t - 1 + kt;
#pragma unroll 1
        for (int kh = 0; kh < 3; ++kh) {
            const int h_in = h - 1 + kh;
            if ((unsigned)h_in >= H_) continue;
            const int rowbase = t_in * HW_ + h_in * W_;
#pragma unroll
            for (int kw = 0; kw < 3; ++kw) {
                const int tap = kt * 9 + kh * 3 + kw;
                const int w_in = wpos - 1 + kw;
                const bool v = (unsigned)w_in < W_;
                const int wc = v ? w_in : 0;
                const __hip_bfloat16* ap = in_cl + (rowbase + wc) * C_ + quad * 8;
                bf16x8 a0 = *(const bf16x8*)(ap);
                bf16x8 a1 = *(const bf16x8*)(ap + 32);
                a0 = v ? a0 : z;
                a1 = v ? a1 : z;
                const __hip_bfloat16* bp = wb + tap * 4096;
                const bf16x8 b00 = *(const bf16x8*)(bp);
                const bf16x8 b01 = *(const bf16x8*)(bp + 512);
                const bf16x8 b10 = *(const bf16x8*)(bp + 1024);
                const bf16x8 b11 = *(const bf16x8*)(bp + 1536);
                acc0 = __builtin_amdgcn_mfma_f32_16x16x32_bf16(a0, b00, acc0, 0, 0, 0);
                acc0 = __builtin_amdgcn_mfma_f32_16x16x32_bf16(a1, b01, acc0, 0, 0, 0);
                acc1 = __builtin_amdgcn_mfma_f32_16x16x32_bf16(a0, b10, acc1, 0, 0, 0);
                acc1 = __builtin_amdgcn_mfma_f32_16x16x32_bf16(a1, b11, acc1, 0, 0, 0);
            }
        }
    }

    const int n0 = chf * 32 + l15;
    const float bv0 = bias[n0], bv1 = bias[n0 + 16];
#pragma unroll
    for (int r = 0; r < 4; ++r) {
        const int p = pg * 16 + quad * 4 + r;
        float v0 = acc0[r] + bv0;
        v0 = (v0 >= 0.f) ? v0 : 0.01f * v0;
        float v1 = acc1[r] + bv1;
        v1 = (v1 >= 0.f) ? v1 : 0.01f * v1;
        ts[p * 72 + n0] = __float2bfloat16(v0);
        ts[p * 72 + n0 + 16] = __float2bfloat16(v1);
    }
    __syncthreads();
    {
        const int p = tid >> 3, ck = tid & 7;
        const uint4 v4 = *(const uint4*)&ts[p * 72 + ck * 8];
        *(uint4*)&out_cl_b16[(posbase + w0 + p) * C_ + ck * 8] = v4;
    }
}

// ---------------------------------------------------------------------------
// FUSED offsets-conv + deform + residual (R28): R12's window-gather structure
// at 2x occupancy. w-split (grid 1024, 32 pos/block, 4 blocks/CU), window
// 5 rows x 38 cols (rows h-2..h+2 suffice: rh = kh+1+floor(dh) <= 3 for
// |dh|<1; fallback covers the rest), offs in bf16 (R7-verified safe).
// LDS 64KB -> 28.6KB. Wave wv: pg=wv&1 (16 pos), oh=wv>>1 (32 outch);
// phase1 = R0's (pos-group x channel-half) split (no duplicated MFMA);
// phase2 gathers duplicate across oh-halves via cheap LDS reads.
// ---------------------------------------------------------------------------
struct G2 {
    bf16x8 a[4];          // 4 corners, channels quad*8 .. +7
    bf16x8 b[4];          // 4 corners, channels 32+quad*8 .. +7
    float w00, w01, w10, w11;
};

__global__ __launch_bounds__(256) void deform_fused_kernel(
    const __hip_bfloat16* __restrict__ y1b,
    const __hip_bfloat16* __restrict__ woffs, const float* __restrict__ boff,
    const __hip_bfloat16* __restrict__ wds, const float* __restrict__ bd,
    const __hip_bfloat16* __restrict__ xclb, const __hip_bfloat16* __restrict__ wrs,
    const float* __restrict__ br, float* __restrict__ out) {
    __shared__ __hip_bfloat16 win[WR_ * WCP * C_];   // 25600 B, chunk-swizzled
    __shared__ __hip_bfloat16 offs[2][16][58];       // 3712 B (bf16, R7-safe)
    // total 29312 B -> 4 blocks/CU (grid-capped), 16 waves/CU

    const int tid = threadIdx.x;
    const int wv = tid >> 6;
    const int lane = tid & 63;
    const int l15 = lane & 15;
    const int quad = lane >> 4;
    DECODE_SWZ_CONV(blockIdx.x, t, h, wh)
    const int w0 = wh * 32;
    const int pg = wv & 1;               // position sub-tile
    const int oh = wv >> 1;              // out-channel half
    const int pw = w0 + pg * 16 + l15;   // this lane's position (w coord)

    const int ktlo = (t == 0) ? 1 : 0;
    const int kthi = (t == T_ - 1) ? 2 : 3;

    // ========== Phase 1: offsets conv, R0 (pos-group x ch-half) split ======
    {
        const int chf = oh;              // offset-channel half
        floatx4 oa0 = (floatx4){0.f, 0.f, 0.f, 0.f};
        floatx4 oa1 = (floatx4){0.f, 0.f, 0.f, 0.f};
        const bf16x8 z = {};
        const __hip_bfloat16* wb = woffs + chf * 2048 + lane * 8;

        for (int kt = ktlo; kt < kthi; ++kt) {
            const int t_in = t - 1 + kt;
#pragma unroll 1
            for (int kh = 0; kh < 3; ++kh) {
                const int h_in = h - 1 + kh;
                if ((unsigned)h_in >= H_) continue;
                const int rowbase = t_in * HW_ + h_in * W_;
#pragma unroll
                for (int kw = 0; kw < 3; ++kw) {
                    const int tap = kt * 9 + kh * 3 + kw;
                    const int w_in = pw - 1 + kw;
                    const bool v = (unsigned)w_in < W_;
                    const int wc = v ? w_in : 0;
                    const __hip_bfloat16* ap = y1b + (rowbase + wc) * C_ + quad * 8;
                    bf16x8 a0 = *(const bf16x8*)(ap);
                    bf16x8 a1 = *(const bf16x8*)(ap + 32);
                    a0 = v ? a0 : z;
                    a1 = v ? a1 : z;
                    const __hip_bfloat16* bp = wb + tap * 4096;
                    const bf16x8 b00 = *(const bf16x8*)(bp);
                    const bf16x8 b01 = *(const bf16x8*)(bp + 512);
                    const bf16x8 b10 = *(const bf16x8*)(bp + 1024);
                    const bf16x8 b11 = *(const bf16x8*)(bp + 1536);
                    oa0 = __builtin_amdgcn_mfma_f32_16x16x32_bf16(a0, b00, oa0, 0, 0, 0);
                    oa0 = __builtin_amdgcn_mfma_f32_16x16x32_bf16(a1, b01, oa0, 0, 0, 0);
                    oa1 = __builtin_amdgcn_mfma_f32_16x16x32_bf16(a0, b10, oa1, 0, 0, 0);
                    oa1 = __builtin_amdgcn_mfma_f32_16x16x32_bf16(a1, b11, oa1, 0, 0, 0);
                }
            }
        }
        const int n0 = chf * 32 + l15;                // 0..15 or 32..47 (<54)
        const float bv0 = boff[n0];
        const float bv1 = (n0 + 16 < NOFF) ? boff[n0 + 16] : 0.f;
#pragma unroll
        for (int r = 0; r < 4; ++r) {
            const int p = quad * 4 + r;               // position within group
            offs[pg][p][n0] = __float2bfloat16(oa0[r] + bv0);
            if (n0 + 16 < NOFF) offs[pg][p][n0 + 16] = __float2bfloat16(oa1[r] + bv1);
        }
    }
    LGKM_BARRIER();    // cross-wave offs publish (both ch-halves per group)

    // ========== Phase 2: window-gather deform + residual ==========
    floatx4 acc[2], racc[2];
#pragma unroll
    for (int g = 0; g < 2; ++g) {
        acc[g] = (floatx4){0.f, 0.f, 0.f, 0.f};
        racc[g] = (floatx4){0.f, 0.f, 0.f, 0.f};
    }

    // residual 1x1 conv: this wave's 16 pos x its 32 outch
    {
        const __hip_bfloat16* ap = xclb + (t * HW_ + h * W_ + pw) * C_ + quad * 8;
        const bf16x8 ra0 = *(const bf16x8*)(ap);
        const bf16x8 ra1 = *(const bf16x8*)(ap + 32);
        const __hip_bfloat16* q = wrs + oh * 2048 + lane * 8;
#pragma unroll
        for (int g = 0; g < 2; ++g) {
            const bf16x8 r0 = *(const bf16x8*)(q + g * 1024);
            const bf16x8 r1 = *(const bf16x8*)(q + g * 1024 + 512);
            racc[g] = __builtin_amdgcn_mfma_f32_16x16x32_bf16(ra0, r0, racc[g], 0, 0, 0);
            racc[g] = __builtin_amdgcn_mfma_f32_16x16x32_bf16(ra1, r1, racc[g], 0, 0, 0);
        }
    }

    auto load_off = [&](int k, float& dh, float& dw) {
        union { uint u; __hip_bfloat16 b[2]; } cv;
        cv.u = *(const uint*)&offs[pg][l15][2 * k];
        dh = __bfloat162float(cv.b[0]);
        dw = __bfloat162float(cv.b[1]);
    };
    // window read: row rr (0..4), window-col cc (0..37), 16B chunk, swizzled
    auto rdwin = [&](int rr, int cc, int chunk) -> bf16x8 {
        const int u = (rr * WCP + cc) * 8 + (chunk ^ (cc & 7));
        return *(const bf16x8*)((const char*)win + u * 16);
    };
    auto gatherW = [&](int k, float dh, float dw, G2& g) {
        const int kh = (k / 3) % 3, kw = k % 3;
        const float hs = (float)(h - 1 + kh) + dh;
        const float wsv = (float)(pw - 1 + kw) + dw;
        const float h0f = floorf(hs), w0f = floorf(wsv);
        const float fh = hs - h0f, fw = wsv - w0f;
        const int h0i = (int)h0f, w0i = (int)w0f;
        const int h1i = h0i + 1, w1i = w0i + 1;
        const float m_h0 = ((unsigned)h0i < H_) ? 1.f : 0.f;
        const float m_h1 = ((unsigned)h1i < H_) ? 1.f : 0.f;
        const float m_w0 = ((unsigned)w0i < W_) ? 1.f : 0.f;
        const float m_w1 = ((unsigned)w1i < W_) ? 1.f : 0.f;
        g.w00 = (1.f - fh) * (1.f - fw) * m_h0 * m_w0;
        g.w01 = (1.f - fh) * fw * m_h0 * m_w1;
        g.w10 = fh * (1.f - fw) * m_h1 * m_w0;
        g.w11 = fh * fw * m_h1 * m_w1;
        const int w0c = min(max(w0i, 0), W_ - 1);
        const int w1c = min(max(w1i, 0), W_ - 1);
        const int rh = h0i - (h - 2);
        const int rw0 = w0c - (w0 - 2);
        const int rw1 = w1c - (w0 - 2);
        if ((unsigned)rh <= 3u && (unsigned)rw0 <= 37u && (unsigned)rw1 <= 37u) {
            g.a[0] = rdwin(rh, rw0, quad);      g.b[0] = rdwin(rh, rw0, quad + 4);
            g.a[1] = rdwin(rh, rw1, quad);      g.b[1] = rdwin(rh, rw1, quad + 4);
            g.a[2] = rdwin(rh + 1, rw0, quad);  g.b[2] = rdwin(rh + 1, rw0, quad + 4);
            g.a[3] = rdwin(rh + 1, rw1, quad);  g.b[3] = rdwin(rh + 1, rw1, quad + 4);
        } else {                                 // rare fallback: R11 global path
            const int h0c = min(max(h0i, 0), H_ - 1);
            const int h1c = min(max(h1i, 0), H_ - 1);
            const int tb = (t - 1 + k / 9) * HW_;
            const __hip_bfloat16* p00 = y1b + (tb + h0c * W_ + w0c) * C_ + quad * 8;
            const __hip_bfloat16* p01 = y1b + (tb + h0c * W_ + w1c) * C_ + quad * 8;
            const __hip_bfloat16* p10 = y1b + (tb + h1c * W_ + w0c) * C_ + quad * 8;
            const __hip_bfloat16* p11 = y1b + (tb + h1c * W_ + w1c) * C_ + quad * 8;
            g.a[0] = *(const bf16x8*)(p00);  g.b[0] = *(const bf16x8*)(p00 + 32);
            g.a[1] = *(const bf16x8*)(p01);  g.b[1] = *(const bf16x8*)(p01 + 32);
            g.a[2] = *(const bf16x8*)(p10);  g.b[2] = *(const bf16x8*)(p10 + 32);
            g.a[3] = *(const bf16x8*)(p11);  g.b[3] = *(const bf16x8*)(p11 + 32);
        }
    };
    auto blend2 = [&](const G2& g, bf16x8& lo, bf16x8& hi) {
        union U { bf16x8 v; __hip_bfloat16 e[8]; };
        U c0, c1, c2, c3, r;
        c0.v = g.a[0]; c1.v = g.a[1]; c2.v = g.a[2]; c3.v = g.a[3];
#pragma unroll
        for (int j = 0; j < 8; ++j) {
            float f = g.w00 * __bfloat162float(c0.e[j]) + g.w01 * __bfloat162float(c1.e[j]) +
                      g.w10 * __bfloat162float(c2.e[j]) + g.w11 * __bfloat162float(c3.e[j]);
            r.e[j] = __float2bfloat16(f);
        }
        lo = r.v;
        c0.v = g.b[0]; c1.v = g.b[1]; c2.v = g.b[2]; c3.v = g.b[3];
#pragma unroll
        for (int j = 0; j < 8; ++j) {
            float f = g.w00 * __bfloat162float(c0.e[j]) + g.w01 * __bfloat162float(c1.e[j]) +
                      g.w10 * __bfloat162float(c2.e[j]) + g.w11 * __bfloat162float(c3.e[j]);
            r.e[j] = __float2bfloat16(f);
        }
        hi = r.v;
    };
    auto tapMFMA = [&](int k, const bf16x8& lo, const bf16x8& hi) {
        const __hip_bfloat16* q = wds + k * 4096 + oh * 2048 + lane * 8;
#pragma unroll
        for (int g = 0; g < 2; ++g) {
            const bf16x8 b0 = *(const bf16x8*)(q + g * 1024);
            const bf16x8 b1 = *(const bf16x8*)(q + g * 1024 + 512);
            acc[g] = __builtin_amdgcn_mfma_f32_16x16x32_bf16(lo, b0, acc[g], 0, 0, 0);
            acc[g] = __builtin_amdgcn_mfma_f32_16x16x32_bf16(hi, b1, acc[g], 0, 0, 0);
        }
    };

    G2 gA, gB;
#pragma unroll 1
    for (int kt = ktlo; kt < kthi; ++kt) {
        const int tin = t - 1 + kt;
        const int kg = kt * 9;

        LGKM_BARRIER();                 // prev group's window reads complete
        // stage window: rows h-2..h+2, cols w0-2..w0+35 (both clamped src)
        for (int i = tid; i < WR_ * WC_ * 8; i += 256) {
            const int rh = i / (WC_ * 8);
            const int rem = i - rh * (WC_ * 8);
            const int rw = rem >> 3;
            const int cc = rem & 7;
            const int hsrc = min(max(h - 2 + rh, 0), H_ - 1);
            const int wsrc = min(max(w0 - 2 + rw, 0), W_ - 1);
            const int u = (rh * WCP + rw) * 8 + (cc ^ (rw & 7));
            *(bf16x8*)((char*)win + u * 16) =
                *(const bf16x8*)&y1b[(tin * HW_ + hsrc * W_ + wsrc) * C_ + cc * 8];
        }
        LGKM_BARRIER();                 // window published

        // 9 taps, 2-slot pipeline within the group
        {
            float dh, dw;
            load_off(kg, dh, dw);
            gatherW(kg, dh, dw, gA);
        }
        int k = kg;
        for (; k + 1 < kg + 9; k += 2) {
            {
                float dh, dw;
                load_off(k + 1, dh, dw);
                gatherW(k + 1, dh, dw, gB);
                bf16x8 lo, hi;
                blend2(gA, lo, hi);
                tapMFMA(k, lo, hi);
            }
            {
                if (k + 2 < kg + 9) {
                    float dh, dw;
                    load_off(k + 2, dh, dw);
                    gatherW(k + 2, dh, dw, gA);
                }
                bf16x8 lo, hi;
                blend2(gB, lo, hi);
                tapMFMA(k + 1, lo, hi);
            }
        }
        {   // 9th tap (odd) — gA valid
            bf16x8 lo, hi;
            blend2(gA, lo, hi);
            tapMFMA(k, lo, hi);
        }
    }

    // epilogue: lrelu(deform + bd) + (residual + br)
#pragma unroll
    for (int g = 0; g < 2; ++g) {
        const int n = oh * 32 + g * 16 + l15;
        const float bdv = bd[n], brv = br[n];
        floatx4 o;
#pragma unroll
        for (int r = 0; r < 4; ++r) {
            float v = acc[g][r] + bdv;
            v = (v >= 0.f) ? v : 0.01f * v;
            o[r] = v + racc[g][r] + brv;
        }
        *(floatx4*)&out[n * THW_ + t * HW_ + h * W_ + w0 + pg * 16 + quad * 4] = o;
    }
}

// ---------------------------------------------------------------------------
extern "C" void kernel_launch(void* const* d_in, const int* in_sizes, int n_in,
                              void* d_out, int out_size, void* d_ws, size_t ws_size,
                              hipStream_t stream) {
    const float* x    = (const float*)d_in[0];
    const float* W1   = (const float*)d_in[1];
    const float* b1   = (const float*)d_in[2];
    const float* Woff = (const float*)d_in[3];
    const float* boff = (const float*)d_in[4];
    const float* Wd   = (const float*)d_in[5];
    const float* bd   = (const float*)d_in[6];
    const float* Wr   = (const float*)d_in[7];
    const float* br   = (const float*)d_in[8];
    float* out = (float*)d_out;

    float* ws = (float*)d_ws;
    __hip_bfloat16* xclb  = (__hip_bfloat16*)(ws);             // 2,097,152 bf16
    __hip_bfloat16* y1b   = (__hip_bfloat16*)(ws + 1048576);   // 2,097,152 bf16
    __hip_bfloat16* w1s   = (__hip_bfloat16*)(ws + 2097152);   //   110,592 bf16
    __hip_bfloat16* woffs = (__hip_bfloat16*)(ws + 2152448);   //   110,592 bf16
    __hip_bfloat16* wdsb  = (__hip_bfloat16*)(ws + 2207744);   //   110,592 bf16
    __hip_bfloat16* wrsb  = (__hip_bfloat16*)(ws + 2263040);   //     4,096 bf16
    // total ~9.1 MB

    prep_tocl_kernel<<<THW_ / 64, 256, 0, stream>>>(
        x, xclb, W1, Woff, Wd, Wr, w1s, woffs, wdsb, wrsb);

    conv_stream_kernel<<<dim3(T_ * H_ * 2), 256, 0, stream>>>(
        xclb, w1s, b1, y1b);

    deform_fused_kernel<<<dim3(T_ * H_ * 2), 256, 0, stream>>>(
        y1b, woffs, boff, wdsb, bd, xclb, wrsb, br, out);
}

// Round 14
// 158.854 us; speedup vs baseline: 1.2043x; 1.2043x over previous
//
#include <hip/hip_runtime.h>
#include <hip/hip_bf16.h>

// Problem constants (B=1)
#define T_ 8
#define H_ 64
#define W_ 64
#define C_ 64
#define HW_ (H_ * W_)          // 4096
#define THW_ (T_ * H_ * W_)    // 32768
#define KTAPS 27
#define KDIM (C_ * KTAPS)      // 1728
#define NOFF 54
#define OSTR2 58               // offs LDS stride (floats)
#define AWC 35                 // conv A-window cols (w0-1..w0+33)
#define AWCP 36                // padded col stride

typedef __bf16 bf16x8 __attribute__((ext_vector_type(8)));
typedef float floatx4 __attribute__((ext_vector_type(4)));

#define LGKM_BARRIER()                                        \
    do {                                                      \
        asm volatile("s_waitcnt lgkmcnt(0)" ::: "memory");    \
        __builtin_amdgcn_s_barrier();                         \
    } while (0)

// h-stripe XCD swizzle (R10-VERIFIED: FETCH 12.6->6.8MB, kept).
#define DECODE_SWZ_CONV(bid, t, h, wh)                        \
    const int hi3_ = (bid) & 7;                               \
    const int rest_ = (bid) >> 3;                             \
    const int wh = rest_ & 1;                                 \
    const int h = hi3_ * 8 + ((rest_ >> 1) & 7);              \
    const int t = rest_ >> 4;
#define DECODE_SWZ_ROW(bid, t, h)                             \
    const int h = ((bid) & 7) * 8 + (((bid) >> 3) & 7);       \
    const int t = (bid) >> 6;

// ---------------------------------------------------------------------------
// prep + to_cl merged (unchanged).
// ---------------------------------------------------------------------------
__global__ __launch_bounds__(256) void prep_tocl_kernel(
    const float* __restrict__ x, __hip_bfloat16* __restrict__ xcl,
    const float* __restrict__ w1, const float* __restrict__ woff,
    const float* __restrict__ wd, const float* __restrict__ wr,
    __hip_bfloat16* __restrict__ w1s, __hip_bfloat16* __restrict__ woffs,
    __hip_bfloat16* __restrict__ wds, __hip_bfloat16* __restrict__ wrs) {
    __shared__ float tile[64][65];
    const int tid = threadIdx.x;

    {
        int i = blockIdx.x * 256 + tid;
        if (i < C_ * KDIM) {
            int j = i & 7, lane = (i >> 3) & 63, s = (i >> 9) & 1, g16 = (i >> 10) & 3, tap = i >> 12;
            int co = g16 * 16 + (lane & 15);
            int cin = s * 32 + (lane >> 4) * 8 + j;
            int src = (co * C_ + cin) * KTAPS + tap;
            w1s[i] = __float2bfloat16(w1[src]);
            woffs[i] = (co < NOFF) ? __float2bfloat16(woff[src]) : __float2bfloat16(0.f);
            wds[i] = __float2bfloat16(wd[src]);
        }
        if (i < C_ * C_) {
            int j = i & 7, lane = (i >> 3) & 63, s = (i >> 9) & 1, g16 = i >> 10;
            int co = g16 * 16 + (lane & 15);
            int cin = s * 32 + (lane >> 4) * 8 + j;
            wrs[i] = __float2bfloat16(wr[co * C_ + cin]);
        }
    }

    const int pos0 = blockIdx.x * 64;
    for (int i = tid; i < 4096; i += 256) {
        int ch = i >> 6, p = i & 63;
        tile[ch][p] = x[ch * THW_ + pos0 + p];
    }
    __syncthreads();
    for (int i = tid; i < 4096; i += 256) {
        int p = i >> 6, ch = i & 63;
        xcl[(pos0 + p) * C_ + ch] = __float2bfloat16(tile[ch][p]);
    }
}

// ---------------------------------------------------------------------------
// Streaming MFMA 3x3x3 conv (conv1), R29: A-operands via LDS window.
//  conv_stream is TA-issue-bound (~6 VMEM lane-req/lane-tap; est ~60us).
//  Stage rows h-1..h+1 x cols w0-1..w0+33 of plane t_in into LDS (13.8KB,
//  chunk-swizzled, R12-verified pattern) and read A-frags via ds_read_b128
//  (separate pipe) — removes 2/6 lane-requests. Identical semantics: staged
//  source clamped, invalid w_in masked to zero exactly as before; invalid
//  h_in rows skipped as before. B-loads unchanged (coalesced, L1-hot).
// ---------------------------------------------------------------------------
__global__ __launch_bounds__(256) void conv_stream_kernel(
    const __hip_bfloat16* __restrict__ in_cl,
    const __hip_bfloat16* __restrict__ wTs,
    const float* __restrict__ bias,
    __hip_bfloat16* __restrict__ out_cl_b16) {
    __shared__ __hip_bfloat16 ts[32 * 72];            // 4608B bounce
    __shared__ __hip_bfloat16 awin[3 * AWCP * C_];    // 13824B A-window

    const int tid = threadIdx.x;
    const int wv = tid >> 6;
    const int lane = tid & 63;
    const int l15 = lane & 15;
    const int quad = lane >> 4;
    DECODE_SWZ_CONV(blockIdx.x, t, h, wh)
    const int w0 = wh * 32;
    const int pg = wv >> 1;
    const int chf = wv & 1;
    const int wpos = w0 + pg * 16 + l15;
    const int posbase = t * HW_ + h * W_;

    floatx4 acc0 = (floatx4){0.f, 0.f, 0.f, 0.f};
    floatx4 acc1 = (floatx4){0.f, 0.f, 0.f, 0.f};
    const bf16x8 z = {};
    const __hip_bfloat16* wb = wTs + chf * 2048 + lane * 8;

    auto rdwin = [&](int rr, int cc, int chunk) -> bf16x8 {
        const int u = (rr * AWCP + cc) * 8 + (chunk ^ (cc & 7));
        return *(const bf16x8*)((const char*)awin + u * 16);
    };

    const int ktlo = (t == 0) ? 1 : 0;
    const int kthi = (t == T_ - 1) ? 2 : 3;

#pragma unroll 1
    for (int kt = ktlo; kt < kthi; ++kt) {
        const int t_in = t - 1 + kt;

        LGKM_BARRIER();                 // prev kt window reads complete
        // stage A-window: rows h-1..h+1, cols w0-1..w0+33 (clamped source)
        for (int i = tid; i < 3 * AWC * 8; i += 256) {
            const int rh = i / (AWC * 8);
            const int rem = i - rh * (AWC * 8);
            const int rw = rem >> 3;
            const int cc = rem & 7;
            const int hsrc = min(max(h - 1 + rh, 0), H_ - 1);
            const int wsrc = min(max(w0 - 1 + rw, 0), W_ - 1);
            const int u = (rh * AWCP + rw) * 8 + (cc ^ (rw & 7));
            *(bf16x8*)((char*)awin + u * 16) =
                *(const bf16x8*)&in_cl[(t_in * HW_ + hsrc * W_ + wsrc) * C_ + cc * 8];
        }
        LGKM_BARRIER();                 // window published

#pragma unroll 1
        for (int kh = 0; kh < 3; ++kh) {
            const int h_in = h - 1 + kh;
            if ((unsigned)h_in >= H_) continue;
#pragma unroll
            for (int kw = 0; kw < 3; ++kw) {
                const int tap = kt * 9 + kh * 3 + kw;
                const int w_in = wpos - 1 + kw;
                const bool v = (unsigned)w_in < W_;
                const int rw = pg * 16 + l15 + kw;    // 0..34, always in-window
                bf16x8 a0 = rdwin(kh, rw, quad);
                bf16x8 a1 = rdwin(kh, rw, quad + 4);
                a0 = v ? a0 : z;
                a1 = v ? a1 : z;
                const __hip_bfloat16* bp = wb + tap * 4096;
                const bf16x8 b00 = *(const bf16x8*)(bp);
                const bf16x8 b01 = *(const bf16x8*)(bp + 512);
                const bf16x8 b10 = *(const bf16x8*)(bp + 1024);
                const bf16x8 b11 = *(const bf16x8*)(bp + 1536);
                acc0 = __builtin_amdgcn_mfma_f32_16x16x32_bf16(a0, b00, acc0, 0, 0, 0);
                acc0 = __builtin_amdgcn_mfma_f32_16x16x32_bf16(a1, b01, acc0, 0, 0, 0);
                acc1 = __builtin_amdgcn_mfma_f32_16x16x32_bf16(a0, b10, acc1, 0, 0, 0);
                acc1 = __builtin_amdgcn_mfma_f32_16x16x32_bf16(a1, b11, acc1, 0, 0, 0);
            }
        }
    }

    const int n0 = chf * 32 + l15;
    const float bv0 = bias[n0], bv1 = bias[n0 + 16];
#pragma unroll
    for (int r = 0; r < 4; ++r) {
        const int p = pg * 16 + quad * 4 + r;
        float v0 = acc0[r] + bv0;
        v0 = (v0 >= 0.f) ? v0 : 0.01f * v0;
        float v1 = acc1[r] + bv1;
        v1 = (v1 >= 0.f) ? v1 : 0.01f * v1;
        ts[p * 72 + n0] = __float2bfloat16(v0);
        ts[p * 72 + n0 + 16] = __float2bfloat16(v1);
    }
    __syncthreads();
    {
        const int p = tid >> 3, ck = tid & 7;
        const uint4 v4 = *(const uint4*)&ts[p * 72 + ck * 8];
        *(uint4*)&out_cl_b16[(posbase + w0 + p) * C_ + ck * 8] = v4;
    }
}

// ---------------------------------------------------------------------------
// FUSED offsets-conv + deform + residual — R12 VERBATIM (verified 67.6us).
// (R13's w-split reverted: its pos-sharing wave split duplicated blend+gather
//  -> 86us. Invariant: one blend per (position, channel-slice).)
// ---------------------------------------------------------------------------
struct G2 {
    bf16x8 a[4];          // 4 corners, channels quad*8 .. +7
    bf16x8 b[4];          // 4 corners, channels 32+quad*8 .. +7
    float w00, w01, w10, w11;
};

__global__ __launch_bounds__(256) void deform_fused_kernel(
    const __hip_bfloat16* __restrict__ y1b,
    const __hip_bfloat16* __restrict__ woffs, const float* __restrict__ boff,
    const __hip_bfloat16* __restrict__ wds, const float* __restrict__ bd,
    const __hip_bfloat16* __restrict__ xclb, const __hip_bfloat16* __restrict__ wrs,
    const float* __restrict__ br, float* __restrict__ out) {
    __shared__ __hip_bfloat16 win[6 * 64 * 64];   // 49152 B, chunk-swizzled
    __shared__ float offs[4][16][OSTR2];          // 14848 B, wave-private

    const int tid = threadIdx.x;
    const int wv = tid >> 6;
    const int lane = tid & 63;
    const int l15 = lane & 15;
    const int quad = lane >> 4;
    DECODE_SWZ_ROW(blockIdx.x, t, h)
    const int posbase = t * HW_ + h * W_;
    const int pw = wv * 16 + l15;            // this lane's position (w coord)

    const int ktlo = (t == 0) ? 1 : 0;
    const int kthi = (t == T_ - 1) ? 2 : 3;

    // ========== Phase 1: per-wave offsets conv (no barrier) ==========
    {
        floatx4 oacc[4];
#pragma unroll
        for (int g = 0; g < 4; ++g) oacc[g] = (floatx4){0.f, 0.f, 0.f, 0.f};
        const bf16x8 z = {};

        for (int kt = ktlo; kt < kthi; ++kt) {
            const int t_in = t - 1 + kt;
#pragma unroll 1
            for (int kh = 0; kh < 3; ++kh) {
                const int h_in = h - 1 + kh;
                if ((unsigned)h_in >= H_) continue;
                const int rowbase = t_in * HW_ + h_in * W_;
#pragma unroll
                for (int kw = 0; kw < 3; ++kw) {
                    const int tap = kt * 9 + kh * 3 + kw;
                    const int w_in = pw - 1 + kw;
                    const bool v = (unsigned)w_in < W_;
                    const int wc = v ? w_in : 0;
                    const __hip_bfloat16* ap = y1b + (rowbase + wc) * C_ + quad * 8;
                    bf16x8 a0 = *(const bf16x8*)(ap);
                    bf16x8 a1 = *(const bf16x8*)(ap + 32);
                    a0 = v ? a0 : z;
                    a1 = v ? a1 : z;
                    const __hip_bfloat16* op = woffs + tap * 4096 + lane * 8;
#pragma unroll
                    for (int g = 0; g < 4; ++g) {
                        const bf16x8 b0 = *(const bf16x8*)(op + g * 1024);
                        const bf16x8 b1 = *(const bf16x8*)(op + g * 1024 + 512);
                        oacc[g] = __builtin_amdgcn_mfma_f32_16x16x32_bf16(a0, b0, oacc[g], 0, 0, 0);
                        oacc[g] = __builtin_amdgcn_mfma_f32_16x16x32_bf16(a1, b1, oacc[g], 0, 0, 0);
                    }
                }
            }
        }
#pragma unroll
        for (int g = 0; g < 4; ++g) {
            const int idx = g * 16 + l15;
            if (idx < NOFF) {
                const float bo = boff[idx];
#pragma unroll
                for (int r = 0; r < 4; ++r)
                    offs[wv][quad * 4 + r][idx] = oacc[g][r] + bo;
            }
        }
    }
    asm volatile("s_waitcnt lgkmcnt(0)" ::: "memory");  // same-wave publish

    // ========== Phase 2: window-gather deform + residual ==========
    floatx4 acc[4], racc[4];
#pragma unroll
    for (int g = 0; g < 4; ++g) {
        acc[g] = (floatx4){0.f, 0.f, 0.f, 0.f};
        racc[g] = (floatx4){0.f, 0.f, 0.f, 0.f};
    }

    // residual 1x1 conv
    {
        const __hip_bfloat16* ap = xclb + (posbase + pw) * C_ + quad * 8;
        const bf16x8 ra0 = *(const bf16x8*)(ap);
        const bf16x8 ra1 = *(const bf16x8*)(ap + 32);
        const __hip_bfloat16* q = wrs + lane * 8;
#pragma unroll
        for (int g = 0; g < 4; ++g) {
            const bf16x8 r0 = *(const bf16x8*)(q + g * 1024);
            const bf16x8 r1 = *(const bf16x8*)(q + g * 1024 + 512);
            racc[g] = __builtin_amdgcn_mfma_f32_16x16x32_bf16(ra0, r0, racc[g], 0, 0, 0);
            racc[g] = __builtin_amdgcn_mfma_f32_16x16x32_bf16(ra1, r1, racc[g], 0, 0, 0);
        }
    }

    auto load_off = [&](int k, float& dh, float& dw) {
        dh = offs[wv][l15][2 * k];
        dw = offs[wv][l15][2 * k + 1];
    };
    auto rdwin = [&](int rr, int cc, int chunk) -> bf16x8 {
        const int u = (rr * 64 + cc) * 8 + (chunk ^ (cc & 7));
        return *(const bf16x8*)((const char*)win + u * 16);
    };
    auto gatherW = [&](int k, float dh, float dw, G2& g) {
        const int kh = (k / 3) % 3, kw = k % 3;
        const float hs = (float)(h - 1 + kh) + dh;
        const float wsv = (float)(pw - 1 + kw) + dw;
        const float h0f = floorf(hs), w0f = floorf(wsv);
        const float fh = hs - h0f, fw = wsv - w0f;
        const int h0i = (int)h0f, w0i = (int)w0f;
        const int h1i = h0i + 1, w1i = w0i + 1;
        const float m_h0 = ((unsigned)h0i < H_) ? 1.f : 0.f;
        const float m_h1 = ((unsigned)h1i < H_) ? 1.f : 0.f;
        const float m_w0 = ((unsigned)w0i < W_) ? 1.f : 0.f;
        const float m_w1 = ((unsigned)w1i < W_) ? 1.f : 0.f;
        g.w00 = (1.f - fh) * (1.f - fw) * m_h0 * m_w0;
        g.w01 = (1.f - fh) * fw * m_h0 * m_w1;
        g.w10 = fh * (1.f - fw) * m_h1 * m_w0;
        g.w11 = fh * fw * m_h1 * m_w1;
        const int w0c = min(max(w0i, 0), W_ - 1);
        const int w1c = min(max(w1i, 0), W_ - 1);
        const int rh = h0i - (h - 2);
        if ((unsigned)rh <= 4u) {               // window path
            g.a[0] = rdwin(rh, w0c, quad);      g.b[0] = rdwin(rh, w0c, quad + 4);
            g.a[1] = rdwin(rh, w1c, quad);      g.b[1] = rdwin(rh, w1c, quad + 4);
            g.a[2] = rdwin(rh + 1, w0c, quad);  g.b[2] = rdwin(rh + 1, w0c, quad + 4);
            g.a[3] = rdwin(rh + 1, w1c, quad);  g.b[3] = rdwin(rh + 1, w1c, quad + 4);
        } else {                                 // rare fallback: global path
            const int h0c = min(max(h0i, 0), H_ - 1);
            const int h1c = min(max(h1i, 0), H_ - 1);
            const int tb = (t - 1 + k / 9) * HW_;
            const __hip_bfloat16* p00 = y1b + (tb + h0c * W_ + w0c) * C_ + quad * 8;
            const __hip_bfloat16* p01 = y1b + (tb + h0c * W_ + w1c) * C_ + quad * 8;
            const __hip_bfloat16* p10 = y1b + (tb + h1c * W_ + w0c) * C_ + quad * 8;
            const __hip_bfloat16* p11 = y1b + (tb + h1c * W_ + w1c) * C_ + quad * 8;
            g.a[0] = *(const bf16x8*)(p00);  g.b[0] = *(const bf16x8*)(p00 + 32);
            g.a[1] = *(const bf16x8*)(p01);  g.b[1] = *(const bf16x8*)(p01 + 32);
            g.a[2] = *(const bf16x8*)(p10);  g.b[2] = *(const bf16x8*)(p10 + 32);
            g.a[3] = *(const bf16x8*)(p11);  g.b[3] = *(const bf16x8*)(p11 + 32);
        }
    };
    auto blend2 = [&](const G2& g, bf16x8& lo, bf16x8& hi) {
        union U { bf16x8 v; __hip_bfloat16 e[8]; };
        U c0, c1, c2, c3, r;
        c0.v = g.a[0]; c1.v = g.a[1]; c2.v = g.a[2]; c3.v = g.a[3];
#pragma unroll
        for (int j = 0; j < 8; ++j) {
            float f = g.w00 * __bfloat162float(c0.e[j]) + g.w01 * __bfloat162float(c1.e[j]) +
                      g.w10 * __bfloat162float(c2.e[j]) + g.w11 * __bfloat162float(c3.e[j]);
            r.e[j] = __float2bfloat16(f);
        }
        lo = r.v;
        c0.v = g.b[0]; c1.v = g.b[1]; c2.v = g.b[2]; c3.v = g.b[3];
#pragma unroll
        for (int j = 0; j < 8; ++j) {
            float f = g.w00 * __bfloat162float(c0.e[j]) + g.w01 * __bfloat162float(c1.e[j]) +
                      g.w10 * __bfloat162float(c2.e[j]) + g.w11 * __bfloat162float(c3.e[j]);
            r.e[j] = __float2bfloat16(f);
        }
        hi = r.v;
    };
    auto tapMFMA = [&](int k, const bf16x8& lo, const bf16x8& hi) {
        const __hip_bfloat16* q = wds + k * 4096 + lane * 8;
#pragma unroll
        for (int g = 0; g < 4; ++g) {
            const bf16x8 b0 = *(const bf16x8*)(q + g * 1024);
            const bf16x8 b1 = *(const bf16x8*)(q + g * 1024 + 512);
            acc[g] = __builtin_amdgcn_mfma_f32_16x16x32_bf16(lo, b0, acc[g], 0, 0, 0);
            acc[g] = __builtin_amdgcn_mfma_f32_16x16x32_bf16(hi, b1, acc[g], 0, 0, 0);
        }
    };

    G2 gA, gB;
#pragma unroll 1
    for (int kt = ktlo; kt < kthi; ++kt) {
        const int tin = t - 1 + kt;
        const int kg = kt * 9;

        LGKM_BARRIER();                 // prev group's window reads complete
        for (int i = tid; i < 6 * 64 * 8; i += 256) {
            const int rh = i >> 9;
            const int rem = i & 511;
            const int rw = rem >> 3;
            const int cc = rem & 7;
            const int hsrc = min(max(h - 2 + rh, 0), H_ - 1);
            const int u = (rh * 64 + rw) * 8 + (cc ^ (rw & 7));
            *(bf16x8*)((char*)win + u * 16) =
                *(const bf16x8*)&y1b[(tin * HW_ + hsrc * W_ + rw) * C_ + cc * 8];
        }
        LGKM_BARRIER();                 // window published

        {
            float dh, dw;
            load_off(kg, dh, dw);
            gatherW(kg, dh, dw, gA);
        }
        int k = kg;
        for (; k + 1 < kg + 9; k += 2) {
            {
                float dh, dw;
                load_off(k + 1, dh, dw);
                gatherW(k + 1, dh, dw, gB);
                bf16x8 lo, hi;
                blend2(gA, lo, hi);
                tapMFMA(k, lo, hi);
            }
            {
                if (k + 2 < kg + 9) {
                    float dh, dw;
                    load_off(k + 2, dh, dw);
                    gatherW(k + 2, dh, dw, gA);
                }
                bf16x8 lo, hi;
                blend2(gB, lo, hi);
                tapMFMA(k + 1, lo, hi);
            }
        }
        {   // 9th tap (odd) — gA valid
            bf16x8 lo, hi;
            blend2(gA, lo, hi);
            tapMFMA(k, lo, hi);
        }
    }

    // epilogue
#pragma unroll
    for (int g = 0; g < 4; ++g) {
        const int n = g * 16 + l15;
        const float bdv = bd[n], brv = br[n];
        floatx4 o;
#pragma unroll
        for (int r = 0; r < 4; ++r) {
            float v = acc[g][r] + bdv;
            v = (v >= 0.f) ? v : 0.01f * v;
            o[r] = v + racc[g][r] + brv;
        }
        *(floatx4*)&out[n * THW_ + posbase + wv * 16 + quad * 4] = o;
    }
}

// ---------------------------------------------------------------------------
extern "C" void kernel_launch(void* const* d_in, const int* in_sizes, int n_in,
                              void* d_out, int out_size, void* d_ws, size_t ws_size,
                              hipStream_t stream) {
    const float* x    = (const float*)d_in[0];
    const float* W1   = (const float*)d_in[1];
    const float* b1   = (const float*)d_in[2];
    const float* Woff = (const float*)d_in[3];
    const float* boff = (const float*)d_in[4];
    const float* Wd   = (const float*)d_in[5];
    const float* bd   = (const float*)d_in[6];
    const float* Wr   = (const float*)d_in[7];
    const float* br   = (const float*)d_in[8];
    float* out = (float*)d_out;

    float* ws = (float*)d_ws;
    __hip_bfloat16* xclb  = (__hip_bfloat16*)(ws);             // 2,097,152 bf16
    __hip_bfloat16* y1b   = (__hip_bfloat16*)(ws + 1048576);   // 2,097,152 bf16
    __hip_bfloat16* w1s   = (__hip_bfloat16*)(ws + 2097152);   //   110,592 bf16
    __hip_bfloat16* woffs = (__hip_bfloat16*)(ws + 2152448);   //   110,592 bf16
    __hip_bfloat16* wdsb  = (__hip_bfloat16*)(ws + 2207744);   //   110,592 bf16
    __hip_bfloat16* wrsb  = (__hip_bfloat16*)(ws + 2263040);   //     4,096 bf16
    // total ~9.1 MB

    prep_tocl_kernel<<<THW_ / 64, 256, 0, stream>>>(
        x, xclb, W1, Woff, Wd, Wr, w1s, woffs, wdsb, wrsb);

    conv_stream_kernel<<<dim3(T_ * H_ * 2), 256, 0, stream>>>(
        xclb, w1s, b1, y1b);

    deform_fused_kernel<<<dim3(T_ * H_), 256, 0, stream>>>(
        y1b, woffs, boff, wdsb, bd, xclb, wrsb, br, out);
}

// Round 15
// 152.137 us; speedup vs baseline: 1.2574x; 1.0442x over previous
//
#include <hip/hip_runtime.h>
#include <hip/hip_bf16.h>

// Problem constants (B=1)
#define T_ 8
#define H_ 64
#define W_ 64
#define C_ 64
#define HW_ (H_ * W_)          // 4096
#define THW_ (T_ * H_ * W_)    // 32768
#define KTAPS 27
#define KDIM (C_ * KTAPS)      // 1728
#define NOFF 54
#define OSTR2 58               // offs LDS stride (floats)
#define AWC 35                 // conv A-window cols (w0-1..w0+33)
#define AWCP 36                // padded col stride

typedef __bf16 bf16x8 __attribute__((ext_vector_type(8)));
typedef float floatx4 __attribute__((ext_vector_type(4)));

#define LGKM_BARRIER()                                        \
    do {                                                      \
        asm volatile("s_waitcnt lgkmcnt(0)" ::: "memory");    \
        __builtin_amdgcn_s_barrier();                         \
    } while (0)

// h-stripe XCD swizzle (R10-VERIFIED: FETCH 12.6->6.8MB, kept).
#define DECODE_SWZ_CONV(bid, t, h, wh)                        \
    const int hi3_ = (bid) & 7;                               \
    const int rest_ = (bid) >> 3;                             \
    const int wh = rest_ & 1;                                 \
    const int h = hi3_ * 8 + ((rest_ >> 1) & 7);              \
    const int t = rest_ >> 4;
#define DECODE_SWZ_ROW(bid, t, h)                             \
    const int h = ((bid) & 7) * 8 + (((bid) >> 3) & 7);       \
    const int t = (bid) >> 6;

// ---------------------------------------------------------------------------
// prep + to_cl merged (unchanged).
// ---------------------------------------------------------------------------
__global__ __launch_bounds__(256) void prep_tocl_kernel(
    const float* __restrict__ x, __hip_bfloat16* __restrict__ xcl,
    const float* __restrict__ w1, const float* __restrict__ woff,
    const float* __restrict__ wd, const float* __restrict__ wr,
    __hip_bfloat16* __restrict__ w1s, __hip_bfloat16* __restrict__ woffs,
    __hip_bfloat16* __restrict__ wds, __hip_bfloat16* __restrict__ wrs) {
    __shared__ float tile[64][65];
    const int tid = threadIdx.x;

    {
        int i = blockIdx.x * 256 + tid;
        if (i < C_ * KDIM) {
            int j = i & 7, lane = (i >> 3) & 63, s = (i >> 9) & 1, g16 = (i >> 10) & 3, tap = i >> 12;
            int co = g16 * 16 + (lane & 15);
            int cin = s * 32 + (lane >> 4) * 8 + j;
            int src = (co * C_ + cin) * KTAPS + tap;
            w1s[i] = __float2bfloat16(w1[src]);
            woffs[i] = (co < NOFF) ? __float2bfloat16(woff[src]) : __float2bfloat16(0.f);
            wds[i] = __float2bfloat16(wd[src]);
        }
        if (i < C_ * C_) {
            int j = i & 7, lane = (i >> 3) & 63, s = (i >> 9) & 1, g16 = i >> 10;
            int co = g16 * 16 + (lane & 15);
            int cin = s * 32 + (lane >> 4) * 8 + j;
            wrs[i] = __float2bfloat16(wr[co * C_ + cin]);
        }
    }

    const int pos0 = blockIdx.x * 64;
    for (int i = tid; i < 4096; i += 256) {
        int ch = i >> 6, p = i & 63;
        tile[ch][p] = x[ch * THW_ + pos0 + p];
    }
    __syncthreads();
    for (int i = tid; i < 4096; i += 256) {
        int p = i >> 6, ch = i & 63;
        xcl[(pos0 + p) * C_ + ch] = __float2bfloat16(tile[ch][p]);
    }
}

// ---------------------------------------------------------------------------
// Streaming MFMA 3x3x3 conv (conv1) — R14 VERBATIM (verified: conv ~-19us).
// ---------------------------------------------------------------------------
__global__ __launch_bounds__(256) void conv_stream_kernel(
    const __hip_bfloat16* __restrict__ in_cl,
    const __hip_bfloat16* __restrict__ wTs,
    const float* __restrict__ bias,
    __hip_bfloat16* __restrict__ out_cl_b16) {
    __shared__ __hip_bfloat16 ts[32 * 72];            // 4608B bounce
    __shared__ __hip_bfloat16 awin[3 * AWCP * C_];    // 13824B A-window

    const int tid = threadIdx.x;
    const int wv = tid >> 6;
    const int lane = tid & 63;
    const int l15 = lane & 15;
    const int quad = lane >> 4;
    DECODE_SWZ_CONV(blockIdx.x, t, h, wh)
    const int w0 = wh * 32;
    const int pg = wv >> 1;
    const int chf = wv & 1;
    const int wpos = w0 + pg * 16 + l15;
    const int posbase = t * HW_ + h * W_;

    floatx4 acc0 = (floatx4){0.f, 0.f, 0.f, 0.f};
    floatx4 acc1 = (floatx4){0.f, 0.f, 0.f, 0.f};
    const bf16x8 z = {};
    const __hip_bfloat16* wb = wTs + chf * 2048 + lane * 8;

    auto rdwin = [&](int rr, int cc, int chunk) -> bf16x8 {
        const int u = (rr * AWCP + cc) * 8 + (chunk ^ (cc & 7));
        return *(const bf16x8*)((const char*)awin + u * 16);
    };

    const int ktlo = (t == 0) ? 1 : 0;
    const int kthi = (t == T_ - 1) ? 2 : 3;

#pragma unroll 1
    for (int kt = ktlo; kt < kthi; ++kt) {
        const int t_in = t - 1 + kt;

        LGKM_BARRIER();                 // prev kt window reads complete
        for (int i = tid; i < 3 * AWC * 8; i += 256) {
            const int rh = i / (AWC * 8);
            const int rem = i - rh * (AWC * 8);
            const int rw = rem >> 3;
            const int cc = rem & 7;
            const int hsrc = min(max(h - 1 + rh, 0), H_ - 1);
            const int wsrc = min(max(w0 - 1 + rw, 0), W_ - 1);
            const int u = (rh * AWCP + rw) * 8 + (cc ^ (rw & 7));
            *(bf16x8*)((char*)awin + u * 16) =
                *(const bf16x8*)&in_cl[(t_in * HW_ + hsrc * W_ + wsrc) * C_ + cc * 8];
        }
        LGKM_BARRIER();                 // window published

#pragma unroll 1
        for (int kh = 0; kh < 3; ++kh) {
            const int h_in = h - 1 + kh;
            if ((unsigned)h_in >= H_) continue;
#pragma unroll
            for (int kw = 0; kw < 3; ++kw) {
                const int tap = kt * 9 + kh * 3 + kw;
                const int w_in = wpos - 1 + kw;
                const bool v = (unsigned)w_in < W_;
                const int rw = pg * 16 + l15 + kw;    // 0..34, always in-window
                bf16x8 a0 = rdwin(kh, rw, quad);
                bf16x8 a1 = rdwin(kh, rw, quad + 4);
                a0 = v ? a0 : z;
                a1 = v ? a1 : z;
                const __hip_bfloat16* bp = wb + tap * 4096;
                const bf16x8 b00 = *(const bf16x8*)(bp);
                const bf16x8 b01 = *(const bf16x8*)(bp + 512);
                const bf16x8 b10 = *(const bf16x8*)(bp + 1024);
                const bf16x8 b11 = *(const bf16x8*)(bp + 1536);
                acc0 = __builtin_amdgcn_mfma_f32_16x16x32_bf16(a0, b00, acc0, 0, 0, 0);
                acc0 = __builtin_amdgcn_mfma_f32_16x16x32_bf16(a1, b01, acc0, 0, 0, 0);
                acc1 = __builtin_amdgcn_mfma_f32_16x16x32_bf16(a0, b10, acc1, 0, 0, 0);
                acc1 = __builtin_amdgcn_mfma_f32_16x16x32_bf16(a1, b11, acc1, 0, 0, 0);
            }
        }
    }

    const int n0 = chf * 32 + l15;
    const float bv0 = bias[n0], bv1 = bias[n0 + 16];
#pragma unroll
    for (int r = 0; r < 4; ++r) {
        const int p = pg * 16 + quad * 4 + r;
        float v0 = acc0[r] + bv0;
        v0 = (v0 >= 0.f) ? v0 : 0.01f * v0;
        float v1 = acc1[r] + bv1;
        v1 = (v1 >= 0.f) ? v1 : 0.01f * v1;
        ts[p * 72 + n0] = __float2bfloat16(v0);
        ts[p * 72 + n0 + 16] = __float2bfloat16(v1);
    }
    __syncthreads();
    {
        const int p = tid >> 3, ck = tid & 7;
        const uint4 v4 = *(const uint4*)&ts[p * 72 + ck * 8];
        *(uint4*)&out_cl_b16[(posbase + w0 + p) * C_ + ck * 8] = v4;
    }
}

// ---------------------------------------------------------------------------
// FUSED offsets-conv + deform + residual (R30): R12 structure, with phase 1's
// A-operands ALSO routed through the LDS window (same transformation just
// verified on conv_stream). Phase 1 must fully precede phase 2 (offsets are
// a 27-tap sum), so: loop A stages a 3-row window per kt (rows h-1..h+1,
// full 64 cols) and runs phase 1's 9 taps with ds_read A-frags; loop B is
// R12's phase 2 verbatim (6-row window). Cost: 3 extra small stages
// (coalesced); saving: ~12.7K scattered VMEM lane-requests per block.
// ---------------------------------------------------------------------------
struct G2 {
    bf16x8 a[4];          // 4 corners, channels quad*8 .. +7
    bf16x8 b[4];          // 4 corners, channels 32+quad*8 .. +7
    float w00, w01, w10, w11;
};

__global__ __launch_bounds__(256) void deform_fused_kernel(
    const __hip_bfloat16* __restrict__ y1b,
    const __hip_bfloat16* __restrict__ woffs, const float* __restrict__ boff,
    const __hip_bfloat16* __restrict__ wds, const float* __restrict__ bd,
    const __hip_bfloat16* __restrict__ xclb, const __hip_bfloat16* __restrict__ wrs,
    const float* __restrict__ br, float* __restrict__ out) {
    __shared__ __hip_bfloat16 win[6 * 64 * 64];   // 49152 B, chunk-swizzled
    __shared__ float offs[4][16][OSTR2];          // 14848 B, wave-private

    const int tid = threadIdx.x;
    const int wv = tid >> 6;
    const int lane = tid & 63;
    const int l15 = lane & 15;
    const int quad = lane >> 4;
    DECODE_SWZ_ROW(blockIdx.x, t, h)
    const int posbase = t * HW_ + h * W_;
    const int pw = wv * 16 + l15;            // this lane's position (w coord)

    const int ktlo = (t == 0) ? 1 : 0;
    const int kthi = (t == T_ - 1) ? 2 : 3;

    auto rdwin = [&](int rr, int cc, int chunk) -> bf16x8 {
        const int u = (rr * 64 + cc) * 8 + (chunk ^ (cc & 7));
        return *(const bf16x8*)((const char*)win + u * 16);
    };

    // ========== Loop A: phase 1 (offsets conv), A via 3-row window ==========
    {
        floatx4 oacc[4];
#pragma unroll
        for (int g = 0; g < 4; ++g) oacc[g] = (floatx4){0.f, 0.f, 0.f, 0.f};
        const bf16x8 z = {};

#pragma unroll 1
        for (int kt = ktlo; kt < kthi; ++kt) {
            const int tin = t - 1 + kt;

            LGKM_BARRIER();             // prev window reads complete
            // stage 3-row window: rows h-1..h+1 (clamped), full 64 cols
            for (int i = tid; i < 3 * 64 * 8; i += 256) {
                const int rh = i >> 9;
                const int rem = i & 511;
                const int rw = rem >> 3;
                const int cc = rem & 7;
                const int hsrc = min(max(h - 1 + rh, 0), H_ - 1);
                const int u = (rh * 64 + rw) * 8 + (cc ^ (rw & 7));
                *(bf16x8*)((char*)win + u * 16) =
                    *(const bf16x8*)&y1b[(tin * HW_ + hsrc * W_ + rw) * C_ + cc * 8];
            }
            LGKM_BARRIER();             // window published

#pragma unroll 1
            for (int kh = 0; kh < 3; ++kh) {
                const int h_in = h - 1 + kh;
                if ((unsigned)h_in >= H_) continue;
#pragma unroll
                for (int kw = 0; kw < 3; ++kw) {
                    const int tap = kt * 9 + kh * 3 + kw;
                    const int w_in = pw - 1 + kw;
                    const bool v = (unsigned)w_in < W_;
                    const int wc = v ? w_in : 0;
                    bf16x8 a0 = rdwin(kh, wc, quad);
                    bf16x8 a1 = rdwin(kh, wc, quad + 4);
                    a0 = v ? a0 : z;
                    a1 = v ? a1 : z;
                    const __hip_bfloat16* op = woffs + tap * 4096 + lane * 8;
#pragma unroll
                    for (int g = 0; g < 4; ++g) {
                        const bf16x8 b0 = *(const bf16x8*)(op + g * 1024);
                        const bf16x8 b1 = *(const bf16x8*)(op + g * 1024 + 512);
                        oacc[g] = __builtin_amdgcn_mfma_f32_16x16x32_bf16(a0, b0, oacc[g], 0, 0, 0);
                        oacc[g] = __builtin_amdgcn_mfma_f32_16x16x32_bf16(a1, b1, oacc[g], 0, 0, 0);
                    }
                }
            }
        }
#pragma unroll
        for (int g = 0; g < 4; ++g) {
            const int idx = g * 16 + l15;
            if (idx < NOFF) {
                const float bo = boff[idx];
#pragma unroll
                for (int r = 0; r < 4; ++r)
                    offs[wv][quad * 4 + r][idx] = oacc[g][r] + bo;
            }
        }
    }
    // offs ds_writes drain inside loop B's first LGKM_BARRIER (same wave)

    // ========== Loop B: phase 2 (R12 verbatim) + residual ==========
    floatx4 acc[4], racc[4];
#pragma unroll
    for (int g = 0; g < 4; ++g) {
        acc[g] = (floatx4){0.f, 0.f, 0.f, 0.f};
        racc[g] = (floatx4){0.f, 0.f, 0.f, 0.f};
    }

    // residual 1x1 conv
    {
        const __hip_bfloat16* ap = xclb + (posbase + pw) * C_ + quad * 8;
        const bf16x8 ra0 = *(const bf16x8*)(ap);
        const bf16x8 ra1 = *(const bf16x8*)(ap + 32);
        const __hip_bfloat16* q = wrs + lane * 8;
#pragma unroll
        for (int g = 0; g < 4; ++g) {
            const bf16x8 r0 = *(const bf16x8*)(q + g * 1024);
            const bf16x8 r1 = *(const bf16x8*)(q + g * 1024 + 512);
            racc[g] = __builtin_amdgcn_mfma_f32_16x16x32_bf16(ra0, r0, racc[g], 0, 0, 0);
            racc[g] = __builtin_amdgcn_mfma_f32_16x16x32_bf16(ra1, r1, racc[g], 0, 0, 0);
        }
    }

    auto load_off = [&](int k, float& dh, float& dw) {
        dh = offs[wv][l15][2 * k];
        dw = offs[wv][l15][2 * k + 1];
    };
    auto gatherW = [&](int k, float dh, float dw, G2& g) {
        const int kh = (k / 3) % 3, kw = k % 3;
        const float hs = (float)(h - 1 + kh) + dh;
        const float wsv = (float)(pw - 1 + kw) + dw;
        const float h0f = floorf(hs), w0f = floorf(wsv);
        const float fh = hs - h0f, fw = wsv - w0f;
        const int h0i = (int)h0f, w0i = (int)w0f;
        const int h1i = h0i + 1, w1i = w0i + 1;
        const float m_h0 = ((unsigned)h0i < H_) ? 1.f : 0.f;
        const float m_h1 = ((unsigned)h1i < H_) ? 1.f : 0.f;
        const float m_w0 = ((unsigned)w0i < W_) ? 1.f : 0.f;
        const float m_w1 = ((unsigned)w1i < W_) ? 1.f : 0.f;
        g.w00 = (1.f - fh) * (1.f - fw) * m_h0 * m_w0;
        g.w01 = (1.f - fh) * fw * m_h0 * m_w1;
        g.w10 = fh * (1.f - fw) * m_h1 * m_w0;
        g.w11 = fh * fw * m_h1 * m_w1;
        const int w0c = min(max(w0i, 0), W_ - 1);
        const int w1c = min(max(w1i, 0), W_ - 1);
        const int rh = h0i - (h - 2);
        if ((unsigned)rh <= 4u) {               // window path
            g.a[0] = rdwin(rh, w0c, quad);      g.b[0] = rdwin(rh, w0c, quad + 4);
            g.a[1] = rdwin(rh, w1c, quad);      g.b[1] = rdwin(rh, w1c, quad + 4);
            g.a[2] = rdwin(rh + 1, w0c, quad);  g.b[2] = rdwin(rh + 1, w0c, quad + 4);
            g.a[3] = rdwin(rh + 1, w1c, quad);  g.b[3] = rdwin(rh + 1, w1c, quad + 4);
        } else {                                 // rare fallback: global path
            const int h0c = min(max(h0i, 0), H_ - 1);
            const int h1c = min(max(h1i, 0), H_ - 1);
            const int tb = (t - 1 + k / 9) * HW_;
            const __hip_bfloat16* p00 = y1b + (tb + h0c * W_ + w0c) * C_ + quad * 8;
            const __hip_bfloat16* p01 = y1b + (tb + h0c * W_ + w1c) * C_ + quad * 8;
            const __hip_bfloat16* p10 = y1b + (tb + h1c * W_ + w0c) * C_ + quad * 8;
            const __hip_bfloat16* p11 = y1b + (tb + h1c * W_ + w1c) * C_ + quad * 8;
            g.a[0] = *(const bf16x8*)(p00);  g.b[0] = *(const bf16x8*)(p00 + 32);
            g.a[1] = *(const bf16x8*)(p01);  g.b[1] = *(const bf16x8*)(p01 + 32);
            g.a[2] = *(const bf16x8*)(p10);  g.b[2] = *(const bf16x8*)(p10 + 32);
            g.a[3] = *(const bf16x8*)(p11);  g.b[3] = *(const bf16x8*)(p11 + 32);
        }
    };
    auto blend2 = [&](const G2& g, bf16x8& lo, bf16x8& hi) {
        union U { bf16x8 v; __hip_bfloat16 e[8]; };
        U c0, c1, c2, c3, r;
        c0.v = g.a[0]; c1.v = g.a[1]; c2.v = g.a[2]; c3.v = g.a[3];
#pragma unroll
        for (int j = 0; j < 8; ++j) {
            float f = g.w00 * __bfloat162float(c0.e[j]) + g.w01 * __bfloat162float(c1.e[j]) +
                      g.w10 * __bfloat162float(c2.e[j]) + g.w11 * __bfloat162float(c3.e[j]);
            r.e[j] = __float2bfloat16(f);
        }
        lo = r.v;
        c0.v = g.b[0]; c1.v = g.b[1]; c2.v = g.b[2]; c3.v = g.b[3];
#pragma unroll
        for (int j = 0; j < 8; ++j) {
            float f = g.w00 * __bfloat162float(c0.e[j]) + g.w01 * __bfloat162float(c1.e[j]) +
                      g.w10 * __bfloat162float(c2.e[j]) + g.w11 * __bfloat162float(c3.e[j]);
            r.e[j] = __float2bfloat16(f);
        }
        hi = r.v;
    };
    auto tapMFMA = [&](int k, const bf16x8& lo, const bf16x8& hi) {
        const __hip_bfloat16* q = wds + k * 4096 + lane * 8;
#pragma unroll
        for (int g = 0; g < 4; ++g) {
            const bf16x8 b0 = *(const bf16x8*)(q + g * 1024);
            const bf16x8 b1 = *(const bf16x8*)(q + g * 1024 + 512);
            acc[g] = __builtin_amdgcn_mfma_f32_16x16x32_bf16(lo, b0, acc[g], 0, 0, 0);
            acc[g] = __builtin_amdgcn_mfma_f32_16x16x32_bf16(hi, b1, acc[g], 0, 0, 0);
        }
    };

    G2 gA, gB;
#pragma unroll 1
    for (int kt = ktlo; kt < kthi; ++kt) {
        const int tin = t - 1 + kt;
        const int kg = kt * 9;

        LGKM_BARRIER();                 // prev group's window reads complete
        for (int i = tid; i < 6 * 64 * 8; i += 256) {
            const int rh = i >> 9;
            const int rem = i & 511;
            const int rw = rem >> 3;
            const int cc = rem & 7;
            const int hsrc = min(max(h - 2 + rh, 0), H_ - 1);
            const int u = (rh * 64 + rw) * 8 + (cc ^ (rw & 7));
            *(bf16x8*)((char*)win + u * 16) =
                *(const bf16x8*)&y1b[(tin * HW_ + hsrc * W_ + rw) * C_ + cc * 8];
        }
        LGKM_BARRIER();                 // window published

        {
            float dh, dw;
            load_off(kg, dh, dw);
            gatherW(kg, dh, dw, gA);
        }
        int k = kg;
        for (; k + 1 < kg + 9; k += 2) {
            {
                float dh, dw;
                load_off(k + 1, dh, dw);
                gatherW(k + 1, dh, dw, gB);
                bf16x8 lo, hi;
                blend2(gA, lo, hi);
                tapMFMA(k, lo, hi);
            }
            {
                if (k + 2 < kg + 9) {
                    float dh, dw;
                    load_off(k + 2, dh, dw);
                    gatherW(k + 2, dh, dw, gA);
                }
                bf16x8 lo, hi;
                blend2(gB, lo, hi);
                tapMFMA(k + 1, lo, hi);
            }
        }
        {   // 9th tap (odd) — gA valid
            bf16x8 lo, hi;
            blend2(gA, lo, hi);
            tapMFMA(k, lo, hi);
        }
    }

    // epilogue
#pragma unroll
    for (int g = 0; g < 4; ++g) {
        const int n = g * 16 + l15;
        const float bdv = bd[n], brv = br[n];
        floatx4 o;
#pragma unroll
        for (int r = 0; r < 4; ++r) {
            float v = acc[g][r] + bdv;
            v = (v >= 0.f) ? v : 0.01f * v;
            o[r] = v + racc[g][r] + brv;
        }
        *(floatx4*)&out[n * THW_ + posbase + wv * 16 + quad * 4] = o;
    }
}

// ---------------------------------------------------------------------------
extern "C" void kernel_launch(void* const* d_in, const int* in_sizes, int n_in,
                              void* d_out, int out_size, void* d_ws, size_t ws_size,
                              hipStream_t stream) {
    const float* x    = (const float*)d_in[0];
    const float* W1   = (const float*)d_in[1];
    const float* b1   = (const float*)d_in[2];
    const float* Woff = (const float*)d_in[3];
    const float* boff = (const float*)d_in[4];
    const float* Wd   = (const float*)d_in[5];
    const float* bd   = (const float*)d_in[6];
    const float* Wr   = (const float*)d_in[7];
    const float* br   = (const float*)d_in[8];
    float* out = (float*)d_out;

    float* ws = (float*)d_ws;
    __hip_bfloat16* xclb  = (__hip_bfloat16*)(ws);             // 2,097,152 bf16
    __hip_bfloat16* y1b   = (__hip_bfloat16*)(ws + 1048576);   // 2,097,152 bf16
    __hip_bfloat16* w1s   = (__hip_bfloat16*)(ws + 2097152);   //   110,592 bf16
    __hip_bfloat16* woffs = (__hip_bfloat16*)(ws + 2152448);   //   110,592 bf16
    __hip_bfloat16* wdsb  = (__hip_bfloat16*)(ws + 2207744);   //   110,592 bf16
    __hip_bfloat16* wrsb  = (__hip_bfloat16*)(ws + 2263040);   //     4,096 bf16
    // total ~9.1 MB

    prep_tocl_kernel<<<THW_ / 64, 256, 0, stream>>>(
        x, xclb, W1, Woff, Wd, Wr, w1s, woffs, wdsb, wrsb);

    conv_stream_kernel<<<dim3(T_ * H_ * 2), 256, 0, stream>>>(
        xclb, w1s, b1, y1b);

    deform_fused_kernel<<<dim3(T_ * H_), 256, 0, stream>>>(
        y1b, woffs, boff, wdsb, bd, xclb, wrsb, br, out);
}

// Round 16
// 150.723 us; speedup vs baseline: 1.2692x; 1.0094x over previous
//
#include <hip/hip_runtime.h>
#include <hip/hip_bf16.h>

// Problem constants (B=1)
#define T_ 8
#define H_ 64
#define W_ 64
#define C_ 64
#define HW_ (H_ * W_)          // 4096
#define THW_ (T_ * H_ * W_)    // 32768
#define KTAPS 27
#define KDIM (C_ * KTAPS)      // 1728
#define NOFF 54
#define OSTR2 58               // offs LDS stride (floats)
#define AWC 35                 // conv A-window cols (w0-1..w0+33)
#define AWCP 36                // padded col stride

typedef __bf16 bf16x8 __attribute__((ext_vector_type(8)));
typedef float floatx4 __attribute__((ext_vector_type(4)));

#define LGKM_BARRIER()                                        \
    do {                                                      \
        asm volatile("s_waitcnt lgkmcnt(0)" ::: "memory");    \
        __builtin_amdgcn_s_barrier();                         \
    } while (0)

// h-stripe XCD swizzle (R10-VERIFIED, kept).
#define DECODE_SWZ_CONV(bid, t, h, wh)                        \
    const int hi3_ = (bid) & 7;                               \
    const int rest_ = (bid) >> 3;                             \
    const int wh = rest_ & 1;                                 \
    const int h = hi3_ * 8 + ((rest_ >> 1) & 7);              \
    const int t = rest_ >> 4;
#define DECODE_SWZ_ROW(bid, t, h)                             \
    const int h = ((bid) & 7) * 8 + (((bid) >> 3) & 7);       \
    const int t = (bid) >> 6;

// ---------------------------------------------------------------------------
// prep + to_cl merged (unchanged).
// ---------------------------------------------------------------------------
__global__ __launch_bounds__(256) void prep_tocl_kernel(
    const float* __restrict__ x, __hip_bfloat16* __restrict__ xcl,
    const float* __restrict__ w1, const float* __restrict__ woff,
    const float* __restrict__ wd, const float* __restrict__ wr,
    __hip_bfloat16* __restrict__ w1s, __hip_bfloat16* __restrict__ woffs,
    __hip_bfloat16* __restrict__ wds, __hip_bfloat16* __restrict__ wrs) {
    __shared__ float tile[64][65];
    const int tid = threadIdx.x;

    {
        int i = blockIdx.x * 256 + tid;
        if (i < C_ * KDIM) {
            int j = i & 7, lane = (i >> 3) & 63, s = (i >> 9) & 1, g16 = (i >> 10) & 3, tap = i >> 12;
            int co = g16 * 16 + (lane & 15);
            int cin = s * 32 + (lane >> 4) * 8 + j;
            int src = (co * C_ + cin) * KTAPS + tap;
            w1s[i] = __float2bfloat16(w1[src]);
            woffs[i] = (co < NOFF) ? __float2bfloat16(woff[src]) : __float2bfloat16(0.f);
            wds[i] = __float2bfloat16(wd[src]);
        }
        if (i < C_ * C_) {
            int j = i & 7, lane = (i >> 3) & 63, s = (i >> 9) & 1, g16 = i >> 10;
            int co = g16 * 16 + (lane & 15);
            int cin = s * 32 + (lane >> 4) * 8 + j;
            wrs[i] = __float2bfloat16(wr[co * C_ + cin]);
        }
    }

    const int pos0 = blockIdx.x * 64;
    for (int i = tid; i < 4096; i += 256) {
        int ch = i >> 6, p = i & 63;
        tile[ch][p] = x[ch * THW_ + pos0 + p];
    }
    __syncthreads();
    for (int i = tid; i < 4096; i += 256) {
        int p = i >> 6, ch = i & 63;
        xcl[(pos0 + p) * C_ + ch] = __float2bfloat16(tile[ch][p]);
    }
}

// ---------------------------------------------------------------------------
// Streaming MFMA 3x3x3 conv (conv1) — R14 VERBATIM (verified).
// ---------------------------------------------------------------------------
__global__ __launch_bounds__(256) void conv_stream_kernel(
    const __hip_bfloat16* __restrict__ in_cl,
    const __hip_bfloat16* __restrict__ wTs,
    const float* __restrict__ bias,
    __hip_bfloat16* __restrict__ out_cl_b16) {
    __shared__ __hip_bfloat16 ts[32 * 72];            // 4608B bounce
    __shared__ __hip_bfloat16 awin[3 * AWCP * C_];    // 13824B A-window

    const int tid = threadIdx.x;
    const int wv = tid >> 6;
    const int lane = tid & 63;
    const int l15 = lane & 15;
    const int quad = lane >> 4;
    DECODE_SWZ_CONV(blockIdx.x, t, h, wh)
    const int w0 = wh * 32;
    const int pg = wv >> 1;
    const int chf = wv & 1;
    const int wpos = w0 + pg * 16 + l15;
    const int posbase = t * HW_ + h * W_;

    floatx4 acc0 = (floatx4){0.f, 0.f, 0.f, 0.f};
    floatx4 acc1 = (floatx4){0.f, 0.f, 0.f, 0.f};
    const bf16x8 z = {};
    const __hip_bfloat16* wb = wTs + chf * 2048 + lane * 8;

    auto rdwin = [&](int rr, int cc, int chunk) -> bf16x8 {
        const int u = (rr * AWCP + cc) * 8 + (chunk ^ (cc & 7));
        return *(const bf16x8*)((const char*)awin + u * 16);
    };

    const int ktlo = (t == 0) ? 1 : 0;
    const int kthi = (t == T_ - 1) ? 2 : 3;

#pragma unroll 1
    for (int kt = ktlo; kt < kthi; ++kt) {
        const int t_in = t - 1 + kt;

        LGKM_BARRIER();                 // prev kt window reads complete
        for (int i = tid; i < 3 * AWC * 8; i += 256) {
            const int rh = i / (AWC * 8);
            const int rem = i - rh * (AWC * 8);
            const int rw = rem >> 3;
            const int cc = rem & 7;
            const int hsrc = min(max(h - 1 + rh, 0), H_ - 1);
            const int wsrc = min(max(w0 - 1 + rw, 0), W_ - 1);
            const int u = (rh * AWCP + rw) * 8 + (cc ^ (rw & 7));
            *(bf16x8*)((char*)awin + u * 16) =
                *(const bf16x8*)&in_cl[(t_in * HW_ + hsrc * W_ + wsrc) * C_ + cc * 8];
        }
        LGKM_BARRIER();                 // window published

#pragma unroll 1
        for (int kh = 0; kh < 3; ++kh) {
            const int h_in = h - 1 + kh;
            if ((unsigned)h_in >= H_) continue;
#pragma unroll
            for (int kw = 0; kw < 3; ++kw) {
                const int tap = kt * 9 + kh * 3 + kw;
                const int w_in = wpos - 1 + kw;
                const bool v = (unsigned)w_in < W_;
                const int rw = pg * 16 + l15 + kw;    // 0..34, always in-window
                bf16x8 a0 = rdwin(kh, rw, quad);
                bf16x8 a1 = rdwin(kh, rw, quad + 4);
                a0 = v ? a0 : z;
                a1 = v ? a1 : z;
                const __hip_bfloat16* bp = wb + tap * 4096;
                const bf16x8 b00 = *(const bf16x8*)(bp);
                const bf16x8 b01 = *(const bf16x8*)(bp + 512);
                const bf16x8 b10 = *(const bf16x8*)(bp + 1024);
                const bf16x8 b11 = *(const bf16x8*)(bp + 1536);
                acc0 = __builtin_amdgcn_mfma_f32_16x16x32_bf16(a0, b00, acc0, 0, 0, 0);
                acc0 = __builtin_amdgcn_mfma_f32_16x16x32_bf16(a1, b01, acc0, 0, 0, 0);
                acc1 = __builtin_amdgcn_mfma_f32_16x16x32_bf16(a0, b10, acc1, 0, 0, 0);
                acc1 = __builtin_amdgcn_mfma_f32_16x16x32_bf16(a1, b11, acc1, 0, 0, 0);
            }
        }
    }

    const int n0 = chf * 32 + l15;
    const float bv0 = bias[n0], bv1 = bias[n0 + 16];
#pragma unroll
    for (int r = 0; r < 4; ++r) {
        const int p = pg * 16 + quad * 4 + r;
        float v0 = acc0[r] + bv0;
        v0 = (v0 >= 0.f) ? v0 : 0.01f * v0;
        float v1 = acc1[r] + bv1;
        v1 = (v1 >= 0.f) ? v1 : 0.01f * v1;
        ts[p * 72 + n0] = __float2bfloat16(v0);
        ts[p * 72 + n0 + 16] = __float2bfloat16(v1);
    }
    __syncthreads();
    {
        const int p = tid >> 3, ck = tid & 7;
        const uint4 v4 = *(const uint4*)&ts[p * 72 + ck * 8];
        *(uint4*)&out_cl_b16[(posbase + w0 + p) * C_ + ck * 8] = v4;
    }
}

// ---------------------------------------------------------------------------
// FUSED offsets-conv + deform + residual (R31): R15 structure with K-SPLIT
// ACROSS WAVES for 2x occupancy. 512-thread blocks (8 waves, grid 512 ->
// 16 waves/CU vs 8). Wave (pg = wv&3, kh2 = wv>>2): 16 positions x K-half.
// Each lane gathers/blends ONLY its K-half chunk (4 ds_reads, 8-ch blend,
// 4 partial MFMAs, 4 B-loads per tap) -> all work totals unchanged,
// parallelism doubled, nothing duplicated (the R5/R13 trap avoided).
// Partial sums reduced elementwise between wave pairs with IDENTICAL
// accumulator layouts (no fragment re-derivation — unlike failed R2):
// phase-1 offsets partials via the (dead) window buffer, final acc/racc
// partials likewise after the last tap.
// ---------------------------------------------------------------------------
struct G1 {
    bf16x8 c[4];          // 4 corners, my K-half chunk only
    float w00, w01, w10, w11;
};

__global__ __launch_bounds__(512, 4) void deform_fused_kernel(
    const __hip_bfloat16* __restrict__ y1b,
    const __hip_bfloat16* __restrict__ woffs, const float* __restrict__ boff,
    const __hip_bfloat16* __restrict__ wds, const float* __restrict__ bd,
    const __hip_bfloat16* __restrict__ xclb, const __hip_bfloat16* __restrict__ wrs,
    const float* __restrict__ br, float* __restrict__ out) {
    __shared__ __hip_bfloat16 win[6 * 64 * 64];   // 49152 B (window + red buf)
    __shared__ float offs[4][16][OSTR2];          // 14848 B

    const int tid = threadIdx.x;
    const int wv = tid >> 6;
    const int lane = tid & 63;
    const int l15 = lane & 15;
    const int quad = lane >> 4;
    DECODE_SWZ_ROW(blockIdx.x, t, h)
    const int posbase = t * HW_ + h * W_;
    const int pg = wv & 3;               // position group (16 pos)
    const int kh2 = wv >> 2;             // K half (input channels kh2*32..)
    const int pw = pg * 16 + l15;        // this lane's position (w coord)
    const int ch = quad + kh2 * 4;       // my K-chunk index (0..7)

    const int ktlo = (t == 0) ? 1 : 0;
    const int kthi = (t == T_ - 1) ? 2 : 3;

    float* winf = (float*)win;

    auto rdwin = [&](int rr, int cc, int chunk) -> bf16x8 {
        const int u = (rr * 64 + cc) * 8 + (chunk ^ (cc & 7));
        return *(const bf16x8*)((const char*)win + u * 16);
    };

    // ========== Loop A: phase 1 (offsets conv), K-split, 3-row window ======
    {
        floatx4 oacc[4];
#pragma unroll
        for (int g = 0; g < 4; ++g) oacc[g] = (floatx4){0.f, 0.f, 0.f, 0.f};
        const bf16x8 z = {};

#pragma unroll 1
        for (int kt = ktlo; kt < kthi; ++kt) {
            const int tin = t - 1 + kt;

            LGKM_BARRIER();             // prev window reads complete
            for (int i = tid; i < 3 * 64 * 8; i += 512) {
                const int rh = i >> 9;
                const int rem = i & 511;
                const int rw = rem >> 3;
                const int cc = rem & 7;
                const int hsrc = min(max(h - 1 + rh, 0), H_ - 1);
                const int u = (rh * 64 + rw) * 8 + (cc ^ (rw & 7));
                *(bf16x8*)((char*)win + u * 16) =
                    *(const bf16x8*)&y1b[(tin * HW_ + hsrc * W_ + rw) * C_ + cc * 8];
            }
            LGKM_BARRIER();             // window published

#pragma unroll 1
            for (int kh = 0; kh < 3; ++kh) {
                const int h_in = h - 1 + kh;
                if ((unsigned)h_in >= H_) continue;
#pragma unroll
                for (int kw = 0; kw < 3; ++kw) {
                    const int tap = kt * 9 + kh * 3 + kw;
                    const int w_in = pw - 1 + kw;
                    const bool v = (unsigned)w_in < W_;
                    const int wc = v ? w_in : 0;
                    bf16x8 a = rdwin(kh, wc, ch);
                    a = v ? a : z;
                    const __hip_bfloat16* op = woffs + tap * 4096 + kh2 * 512 + lane * 8;
#pragma unroll
                    for (int g = 0; g < 4; ++g) {
                        const bf16x8 b = *(const bf16x8*)(op + g * 1024);
                        oacc[g] = __builtin_amdgcn_mfma_f32_16x16x32_bf16(a, b, oacc[g], 0, 0, 0);
                    }
                }
            }
        }
        // K-half reduction (identical layouts, elementwise)
        LGKM_BARRIER();                 // all window reads done -> win reusable
        if (kh2 == 1) {
#pragma unroll
            for (int g = 0; g < 4; ++g)
                *(floatx4*)&winf[(pg * 64 + lane) * 16 + g * 4] = oacc[g];
        }
        LGKM_BARRIER();
        if (kh2 == 0) {
#pragma unroll
            for (int g = 0; g < 4; ++g) {
                const floatx4 p4 = *(const floatx4*)&winf[(pg * 64 + lane) * 16 + g * 4];
                oacc[g] += p4;
                const int idx = g * 16 + l15;
                if (idx < NOFF) {
                    const float bo = boff[idx];
#pragma unroll
                    for (int r = 0; r < 4; ++r)
                        offs[pg][quad * 4 + r][idx] = oacc[g][r] + bo;
                }
            }
        }
    }
    // offs + win handoff published at loop B's first LGKM_BARRIER

    // ========== Loop B: phase 2 (window gather, K-split) + residual ========
    floatx4 acc[4], racc[4];
#pragma unroll
    for (int g = 0; g < 4; ++g) {
        acc[g] = (floatx4){0.f, 0.f, 0.f, 0.f};
        racc[g] = (floatx4){0.f, 0.f, 0.f, 0.f};
    }

    // residual 1x1 conv, K-half partial
    {
        const bf16x8 ra = *(const bf16x8*)(xclb + (posbase + pw) * C_ + ch * 8);
        const __hip_bfloat16* q = wrs + kh2 * 512 + lane * 8;
#pragma unroll
        for (int g = 0; g < 4; ++g) {
            const bf16x8 r0 = *(const bf16x8*)(q + g * 1024);
            racc[g] = __builtin_amdgcn_mfma_f32_16x16x32_bf16(ra, r0, racc[g], 0, 0, 0);
        }
    }

    auto load_off = [&](int k, float& dh, float& dw) {
        dh = offs[pg][l15][2 * k];
        dw = offs[pg][l15][2 * k + 1];
    };
    auto gatherW = [&](int k, float dh, float dw, G1& g) {
        const int kh = (k / 3) % 3, kw = k % 3;
        const float hs = (float)(h - 1 + kh) + dh;
        const float wsv = (float)(pw - 1 + kw) + dw;
        const float h0f = floorf(hs), w0f = floorf(wsv);
        const float fh = hs - h0f, fw = wsv - w0f;
        const int h0i = (int)h0f, w0i = (int)w0f;
        const int h1i = h0i + 1, w1i = w0i + 1;
        const float m_h0 = ((unsigned)h0i < H_) ? 1.f : 0.f;
        const float m_h1 = ((unsigned)h1i < H_) ? 1.f : 0.f;
        const float m_w0 = ((unsigned)w0i < W_) ? 1.f : 0.f;
        const float m_w1 = ((unsigned)w1i < W_) ? 1.f : 0.f;
        g.w00 = (1.f - fh) * (1.f - fw) * m_h0 * m_w0;
        g.w01 = (1.f - fh) * fw * m_h0 * m_w1;
        g.w10 = fh * (1.f - fw) * m_h1 * m_w0;
        g.w11 = fh * fw * m_h1 * m_w1;
        const int w0c = min(max(w0i, 0), W_ - 1);
        const int w1c = min(max(w1i, 0), W_ - 1);
        const int rh = h0i - (h - 2);
        if ((unsigned)rh <= 4u) {               // window path
            g.c[0] = rdwin(rh, w0c, ch);
            g.c[1] = rdwin(rh, w1c, ch);
            g.c[2] = rdwin(rh + 1, w0c, ch);
            g.c[3] = rdwin(rh + 1, w1c, ch);
        } else {                                 // rare fallback: global path
            const int h0c = min(max(h0i, 0), H_ - 1);
            const int h1c = min(max(h1i, 0), H_ - 1);
            const int tb = (t - 1 + k / 9) * HW_;
            g.c[0] = *(const bf16x8*)(y1b + (tb + h0c * W_ + w0c) * C_ + ch * 8);
            g.c[1] = *(const bf16x8*)(y1b + (tb + h0c * W_ + w1c) * C_ + ch * 8);
            g.c[2] = *(const bf16x8*)(y1b + (tb + h1c * W_ + w0c) * C_ + ch * 8);
            g.c[3] = *(const bf16x8*)(y1b + (tb + h1c * W_ + w1c) * C_ + ch * 8);
        }
    };
    auto blend1 = [&](const G1& g, bf16x8& fr) {
        union U { bf16x8 v; __hip_bfloat16 e[8]; };
        U c0, c1, c2, c3, r;
        c0.v = g.c[0]; c1.v = g.c[1]; c2.v = g.c[2]; c3.v = g.c[3];
#pragma unroll
        for (int j = 0; j < 8; ++j) {
            float f = g.w00 * __bfloat162float(c0.e[j]) + g.w01 * __bfloat162float(c1.e[j]) +
                      g.w10 * __bfloat162float(c2.e[j]) + g.w11 * __bfloat162float(c3.e[j]);
            r.e[j] = __float2bfloat16(f);
        }
        fr = r.v;
    };
    auto tapMFMA = [&](int k, const bf16x8& fr) {
        const __hip_bfloat16* q = wds + k * 4096 + kh2 * 512 + lane * 8;
#pragma unroll
        for (int g = 0; g < 4; ++g) {
            const bf16x8 b = *(const bf16x8*)(q + g * 1024);
            acc[g] = __builtin_amdgcn_mfma_f32_16x16x32_bf16(fr, b, acc[g], 0, 0, 0);
        }
    };

    G1 gA, gB;
#pragma unroll 1
    for (int kt = ktlo; kt < kthi; ++kt) {
        const int tin = t - 1 + kt;
        const int kg = kt * 9;

        LGKM_BARRIER();                 // prev group's window reads complete
        for (int i = tid; i < 6 * 64 * 8; i += 512) {
            const int rh = i >> 9;
            const int rem = i & 511;
            const int rw = rem >> 3;
            const int cc = rem & 7;
            const int hsrc = min(max(h - 2 + rh, 0), H_ - 1);
            const int u = (rh * 64 + rw) * 8 + (cc ^ (rw & 7));
            *(bf16x8*)((char*)win + u * 16) =
                *(const bf16x8*)&y1b[(tin * HW_ + hsrc * W_ + rw) * C_ + cc * 8];
        }
        LGKM_BARRIER();                 // window published

        {
            float dh, dw;
            load_off(kg, dh, dw);
            gatherW(kg, dh, dw, gA);
        }
        int k = kg;
        for (; k + 1 < kg + 9; k += 2) {
            {
                float dh, dw;
                load_off(k + 1, dh, dw);
                gatherW(k + 1, dh, dw, gB);
                bf16x8 fr;
                blend1(gA, fr);
                tapMFMA(k, fr);
            }
            {
                if (k + 2 < kg + 9) {
                    float dh, dw;
                    load_off(k + 2, dh, dw);
                    gatherW(k + 2, dh, dw, gA);
                }
                bf16x8 fr;
                blend1(gB, fr);
                tapMFMA(k + 1, fr);
            }
        }
        {   // 9th tap (odd) — gA valid
            bf16x8 fr;
            blend1(gA, fr);
            tapMFMA(k, fr);
        }
    }

    // ========== Final K-half reduction + epilogue ==========
    LGKM_BARRIER();                     // all window reads done -> win reusable
    if (kh2 == 1) {
#pragma unroll
        for (int g = 0; g < 4; ++g) {
            *(floatx4*)&winf[(pg * 64 + lane) * 32 + g * 4] = acc[g];
            *(floatx4*)&winf[(pg * 64 + lane) * 32 + 16 + g * 4] = racc[g];
        }
    }
    LGKM_BARRIER();
    if (kh2 == 0) {
#pragma unroll
        for (int g = 0; g < 4; ++g) {
            const floatx4 pa = *(const floatx4*)&winf[(pg * 64 + lane) * 32 + g * 4];
            const floatx4 pr = *(const floatx4*)&winf[(pg * 64 + lane) * 32 + 16 + g * 4];
            const int n = g * 16 + l15;
            const float bdv = bd[n], brv = br[n];
            floatx4 o;
#pragma unroll
            for (int r = 0; r < 4; ++r) {
                float v = acc[g][r] + pa[r] + bdv;
                v = (v >= 0.f) ? v : 0.01f * v;
                o[r] = v + racc[g][r] + pr[r] + brv;
            }
            *(floatx4*)&out[n * THW_ + posbase + pg * 16 + quad * 4] = o;
        }
    }
}

// ---------------------------------------------------------------------------
extern "C" void kernel_launch(void* const* d_in, const int* in_sizes, int n_in,
                              void* d_out, int out_size, void* d_ws, size_t ws_size,
                              hipStream_t stream) {
    const float* x    = (const float*)d_in[0];
    const float* W1   = (const float*)d_in[1];
    const float* b1   = (const float*)d_in[2];
    const float* Woff = (const float*)d_in[3];
    const float* boff = (const float*)d_in[4];
    const float* Wd   = (const float*)d_in[5];
    const float* bd   = (const float*)d_in[6];
    const float* Wr   = (const float*)d_in[7];
    const float* br   = (const float*)d_in[8];
    float* out = (float*)d_out;

    float* ws = (float*)d_ws;
    __hip_bfloat16* xclb  = (__hip_bfloat16*)(ws);             // 2,097,152 bf16
    __hip_bfloat16* y1b   = (__hip_bfloat16*)(ws + 1048576);   // 2,097,152 bf16
    __hip_bfloat16* w1s   = (__hip_bfloat16*)(ws + 2097152);   //   110,592 bf16
    __hip_bfloat16* woffs = (__hip_bfloat16*)(ws + 2152448);   //   110,592 bf16
    __hip_bfloat16* wdsb  = (__hip_bfloat16*)(ws + 2207744);   //   110,592 bf16
    __hip_bfloat16* wrsb  = (__hip_bfloat16*)(ws + 2263040);   //     4,096 bf16
    // total ~9.1 MB

    prep_tocl_kernel<<<THW_ / 64, 256, 0, stream>>>(
        x, xclb, W1, Woff, Wd, Wr, w1s, woffs, wdsb, wrsb);

    conv_stream_kernel<<<dim3(T_ * H_ * 2), 256, 0, stream>>>(
        xclb, w1s, b1, y1b);

    deform_fused_kernel<<<dim3(T_ * H_), 512, 0, stream>>>(
        y1b, woffs, boff, wdsb, bd, xclb, wrsb, br, out);
}

// Round 18
// 146.185 us; speedup vs baseline: 1.3086x; 1.0310x over previous
//
#include <hip/hip_runtime.h>
#include <hip/hip_bf16.h>

// Problem constants (B=1)
#define T_ 8
#define H_ 64
#define W_ 64
#define C_ 64
#define HW_ (H_ * W_)          // 4096
#define THW_ (T_ * H_ * W_)    // 32768
#define KTAPS 27
#define KDIM (C_ * KTAPS)      // 1728
#define NOFF 54
#define OSTR2 58               // offs LDS stride (floats)
#define AWC 35                 // conv A-window cols (w0-1..w0+33)
#define AWCP 36                // padded col stride

typedef __bf16 bf16x8 __attribute__((ext_vector_type(8)));
typedef float floatx4 __attribute__((ext_vector_type(4)));

#define LGKM_BARRIER()                                        \
    do {                                                      \
        asm volatile("s_waitcnt lgkmcnt(0)" ::: "memory");    \
        __builtin_amdgcn_s_barrier();                         \
    } while (0)

// h-stripe XCD swizzle (R10-VERIFIED, kept).
#define DECODE_SWZ_CONV(bid, t, h, wh)                        \
    const int hi3_ = (bid) & 7;                               \
    const int rest_ = (bid) >> 3;                             \
    const int wh = rest_ & 1;                                 \
    const int h = hi3_ * 8 + ((rest_ >> 1) & 7);              \
    const int t = rest_ >> 4;
#define DECODE_SWZ_ROW(bid, t, h)                             \
    const int h = ((bid) & 7) * 8 + (((bid) >> 3) & 7);       \
    const int t = (bid) >> 6;

// ---------------------------------------------------------------------------
// prep + to_cl merged (unchanged).
// ---------------------------------------------------------------------------
__global__ __launch_bounds__(256) void prep_tocl_kernel(
    const float* __restrict__ x, __hip_bfloat16* __restrict__ xcl,
    const float* __restrict__ w1, const float* __restrict__ woff,
    const float* __restrict__ wd, const float* __restrict__ wr,
    __hip_bfloat16* __restrict__ w1s, __hip_bfloat16* __restrict__ woffs,
    __hip_bfloat16* __restrict__ wds, __hip_bfloat16* __restrict__ wrs) {
    __shared__ float tile[64][65];
    const int tid = threadIdx.x;

    {
        int i = blockIdx.x * 256 + tid;
        if (i < C_ * KDIM) {
            int j = i & 7, lane = (i >> 3) & 63, s = (i >> 9) & 1, g16 = (i >> 10) & 3, tap = i >> 12;
            int co = g16 * 16 + (lane & 15);
            int cin = s * 32 + (lane >> 4) * 8 + j;
            int src = (co * C_ + cin) * KTAPS + tap;
            w1s[i] = __float2bfloat16(w1[src]);
            woffs[i] = (co < NOFF) ? __float2bfloat16(woff[src]) : __float2bfloat16(0.f);
            wds[i] = __float2bfloat16(wd[src]);
        }
        if (i < C_ * C_) {
            int j = i & 7, lane = (i >> 3) & 63, s = (i >> 9) & 1, g16 = i >> 10;
            int co = g16 * 16 + (lane & 15);
            int cin = s * 32 + (lane >> 4) * 8 + j;
            wrs[i] = __float2bfloat16(wr[co * C_ + cin]);
        }
    }

    const int pos0 = blockIdx.x * 64;
    for (int i = tid; i < 4096; i += 256) {
        int ch = i >> 6, p = i & 63;
        tile[ch][p] = x[ch * THW_ + pos0 + p];
    }
    __syncthreads();
    for (int i = tid; i < 4096; i += 256) {
        int p = i >> 6, ch = i & 63;
        xcl[(pos0 + p) * C_ + ch] = __float2bfloat16(tile[ch][p]);
    }
}

// ---------------------------------------------------------------------------
// Streaming MFMA 3x3x3 conv (conv1) — R14 VERBATIM (verified).
// ---------------------------------------------------------------------------
__global__ __launch_bounds__(256) void conv_stream_kernel(
    const __hip_bfloat16* __restrict__ in_cl,
    const __hip_bfloat16* __restrict__ wTs,
    const float* __restrict__ bias,
    __hip_bfloat16* __restrict__ out_cl_b16) {
    __shared__ __hip_bfloat16 ts[32 * 72];            // 4608B bounce
    __shared__ __hip_bfloat16 awin[3 * AWCP * C_];    // 13824B A-window

    const int tid = threadIdx.x;
    const int wv = tid >> 6;
    const int lane = tid & 63;
    const int l15 = lane & 15;
    const int quad = lane >> 4;
    DECODE_SWZ_CONV(blockIdx.x, t, h, wh)
    const int w0 = wh * 32;
    const int pg = wv >> 1;
    const int chf = wv & 1;
    const int wpos = w0 + pg * 16 + l15;
    const int posbase = t * HW_ + h * W_;

    floatx4 acc0 = (floatx4){0.f, 0.f, 0.f, 0.f};
    floatx4 acc1 = (floatx4){0.f, 0.f, 0.f, 0.f};
    const bf16x8 z = {};
    const __hip_bfloat16* wb = wTs + chf * 2048 + lane * 8;

    auto rdwin = [&](int rr, int cc, int chunk) -> bf16x8 {
        const int u = (rr * AWCP + cc) * 8 + (chunk ^ (cc & 7));
        return *(const bf16x8*)((const char*)awin + u * 16);
    };

    const int ktlo = (t == 0) ? 1 : 0;
    const int kthi = (t == T_ - 1) ? 2 : 3;

#pragma unroll 1
    for (int kt = ktlo; kt < kthi; ++kt) {
        const int t_in = t - 1 + kt;

        LGKM_BARRIER();                 // prev kt window reads complete
        for (int i = tid; i < 3 * AWC * 8; i += 256) {
            const int rh = i / (AWC * 8);
            const int rem = i - rh * (AWC * 8);
            const int rw = rem >> 3;
            const int cc = rem & 7;
            const int hsrc = min(max(h - 1 + rh, 0), H_ - 1);
            const int wsrc = min(max(w0 - 1 + rw, 0), W_ - 1);
            const int u = (rh * AWCP + rw) * 8 + (cc ^ (rw & 7));
            *(bf16x8*)((char*)awin + u * 16) =
                *(const bf16x8*)&in_cl[(t_in * HW_ + hsrc * W_ + wsrc) * C_ + cc * 8];
        }
        LGKM_BARRIER();                 // window published

#pragma unroll 1
        for (int kh = 0; kh < 3; ++kh) {
            const int h_in = h - 1 + kh;
            if ((unsigned)h_in >= H_) continue;
#pragma unroll
            for (int kw = 0; kw < 3; ++kw) {
                const int tap = kt * 9 + kh * 3 + kw;
                const int w_in = wpos - 1 + kw;
                const bool v = (unsigned)w_in < W_;
                const int rw = pg * 16 + l15 + kw;    // 0..34, always in-window
                bf16x8 a0 = rdwin(kh, rw, quad);
                bf16x8 a1 = rdwin(kh, rw, quad + 4);
                a0 = v ? a0 : z;
                a1 = v ? a1 : z;
                const __hip_bfloat16* bp = wb + tap * 4096;
                const bf16x8 b00 = *(const bf16x8*)(bp);
                const bf16x8 b01 = *(const bf16x8*)(bp + 512);
                const bf16x8 b10 = *(const bf16x8*)(bp + 1024);
                const bf16x8 b11 = *(const bf16x8*)(bp + 1536);
                acc0 = __builtin_amdgcn_mfma_f32_16x16x32_bf16(a0, b00, acc0, 0, 0, 0);
                acc0 = __builtin_amdgcn_mfma_f32_16x16x32_bf16(a1, b01, acc0, 0, 0, 0);
                acc1 = __builtin_amdgcn_mfma_f32_16x16x32_bf16(a0, b10, acc1, 0, 0, 0);
                acc1 = __builtin_amdgcn_mfma_f32_16x16x32_bf16(a1, b11, acc1, 0, 0, 0);
            }
        }
    }

    const int n0 = chf * 32 + l15;
    const float bv0 = bias[n0], bv1 = bias[n0 + 16];
#pragma unroll
    for (int r = 0; r < 4; ++r) {
        const int p = pg * 16 + quad * 4 + r;
        float v0 = acc0[r] + bv0;
        v0 = (v0 >= 0.f) ? v0 : 0.01f * v0;
        float v1 = acc1[r] + bv1;
        v1 = (v1 >= 0.f) ? v1 : 0.01f * v1;
        ts[p * 72 + n0] = __float2bfloat16(v0);
        ts[p * 72 + n0 + 16] = __float2bfloat16(v1);
    }
    __syncthreads();
    {
        const int p = tid >> 3, ck = tid & 7;
        const uint4 v4 = *(const uint4*)&ts[p * 72 + ck * 8];
        *(uint4*)&out_cl_b16[(posbase + w0 + p) * C_ + ck * 8] = v4;
    }
}

// ---------------------------------------------------------------------------
// FUSED offsets-conv + deform + residual (R33): R16 K-split structure
// (verified 59.9us) + B-FRAGMENT PREFETCH one tap ahead. Previously the 4
// wds B-loads sat between blend and MFMA inside each tap — a serialized
// ~200cy L2 round-trip per tap. Now loadB(k+1) issues alongside
// gatherW(k+1), a full tap of cover, in named registers (+32 VGPR, still
// <128 for 16 waves/CU). Everything else verbatim R16.
// (R17 post-mortem: cooperative grid.sync does NOT give cross-XCD
//  visibility for plain stores on gfx950 — G16 confirmed; fusion reverted.)
// ---------------------------------------------------------------------------
struct G1 {
    bf16x8 c[4];          // 4 corners, my K-half chunk only
    float w00, w01, w10, w11;
};

__global__ __launch_bounds__(512, 4) void deform_fused_kernel(
    const __hip_bfloat16* __restrict__ y1b,
    const __hip_bfloat16* __restrict__ woffs, const float* __restrict__ boff,
    const __hip_bfloat16* __restrict__ wds, const float* __restrict__ bd,
    const __hip_bfloat16* __restrict__ xclb, const __hip_bfloat16* __restrict__ wrs,
    const float* __restrict__ br, float* __restrict__ out) {
    __shared__ __hip_bfloat16 win[6 * 64 * 64];   // 49152 B (window + red buf)
    __shared__ float offs[4][16][OSTR2];          // 14848 B

    const int tid = threadIdx.x;
    const int wv = tid >> 6;
    const int lane = tid & 63;
    const int l15 = lane & 15;
    const int quad = lane >> 4;
    DECODE_SWZ_ROW(blockIdx.x, t, h)
    const int posbase = t * HW_ + h * W_;
    const int pg = wv & 3;               // position group (16 pos)
    const int kh2 = wv >> 2;             // K half (input channels kh2*32..)
    const int pw = pg * 16 + l15;        // this lane's position (w coord)
    const int ch = quad + kh2 * 4;       // my K-chunk index (0..7)

    const int ktlo = (t == 0) ? 1 : 0;
    const int kthi = (t == T_ - 1) ? 2 : 3;

    float* winf = (float*)win;

    auto rdwin = [&](int rr, int cc, int chunk) -> bf16x8 {
        const int u = (rr * 64 + cc) * 8 + (chunk ^ (cc & 7));
        return *(const bf16x8*)((const char*)win + u * 16);
    };

    // ========== Loop A: phase 1 (offsets conv), K-split, 3-row window ======
    {
        floatx4 oacc[4];
#pragma unroll
        for (int g = 0; g < 4; ++g) oacc[g] = (floatx4){0.f, 0.f, 0.f, 0.f};
        const bf16x8 z = {};

#pragma unroll 1
        for (int kt = ktlo; kt < kthi; ++kt) {
            const int tin = t - 1 + kt;

            LGKM_BARRIER();             // prev window reads complete
            for (int i = tid; i < 3 * 64 * 8; i += 512) {
                const int rh = i >> 9;
                const int rem = i & 511;
                const int rw = rem >> 3;
                const int cc = rem & 7;
                const int hsrc = min(max(h - 1 + rh, 0), H_ - 1);
                const int u = (rh * 64 + rw) * 8 + (cc ^ (rw & 7));
                *(bf16x8*)((char*)win + u * 16) =
                    *(const bf16x8*)&y1b[(tin * HW_ + hsrc * W_ + rw) * C_ + cc * 8];
            }
            LGKM_BARRIER();             // window published

#pragma unroll 1
            for (int kh = 0; kh < 3; ++kh) {
                const int h_in = h - 1 + kh;
                if ((unsigned)h_in >= H_) continue;
#pragma unroll
                for (int kw = 0; kw < 3; ++kw) {
                    const int tap = kt * 9 + kh * 3 + kw;
                    const int w_in = pw - 1 + kw;
                    const bool v = (unsigned)w_in < W_;
                    const int wc = v ? w_in : 0;
                    bf16x8 a = rdwin(kh, wc, ch);
                    a = v ? a : z;
                    const __hip_bfloat16* op = woffs + tap * 4096 + kh2 * 512 + lane * 8;
#pragma unroll
                    for (int g = 0; g < 4; ++g) {
                        const bf16x8 b = *(const bf16x8*)(op + g * 1024);
                        oacc[g] = __builtin_amdgcn_mfma_f32_16x16x32_bf16(a, b, oacc[g], 0, 0, 0);
                    }
                }
            }
        }
        // K-half reduction (identical layouts, elementwise)
        LGKM_BARRIER();                 // all window reads done -> win reusable
        if (kh2 == 1) {
#pragma unroll
            for (int g = 0; g < 4; ++g)
                *(floatx4*)&winf[(pg * 64 + lane) * 16 + g * 4] = oacc[g];
        }
        LGKM_BARRIER();
        if (kh2 == 0) {
#pragma unroll
            for (int g = 0; g < 4; ++g) {
                const floatx4 p4 = *(const floatx4*)&winf[(pg * 64 + lane) * 16 + g * 4];
                oacc[g] += p4;
                const int idx = g * 16 + l15;
                if (idx < NOFF) {
                    const float bo = boff[idx];
#pragma unroll
                    for (int r = 0; r < 4; ++r)
                        offs[pg][quad * 4 + r][idx] = oacc[g][r] + bo;
                }
            }
        }
    }
    // offs + win handoff published at loop B's first LGKM_BARRIER

    // ========== Loop B: phase 2 (window gather, K-split) + residual ========
    floatx4 acc[4], racc[4];
#pragma unroll
    for (int g = 0; g < 4; ++g) {
        acc[g] = (floatx4){0.f, 0.f, 0.f, 0.f};
        racc[g] = (floatx4){0.f, 0.f, 0.f, 0.f};
    }

    // residual 1x1 conv, K-half partial
    {
        const bf16x8 ra = *(const bf16x8*)(xclb + (posbase + pw) * C_ + ch * 8);
        const __hip_bfloat16* q = wrs + kh2 * 512 + lane * 8;
#pragma unroll
        for (int g = 0; g < 4; ++g) {
            const bf16x8 r0 = *(const bf16x8*)(q + g * 1024);
            racc[g] = __builtin_amdgcn_mfma_f32_16x16x32_bf16(ra, r0, racc[g], 0, 0, 0);
        }
    }

    auto load_off = [&](int k, float& dh, float& dw) {
        dh = offs[pg][l15][2 * k];
        dw = offs[pg][l15][2 * k + 1];
    };
    auto gatherW = [&](int k, float dh, float dw, G1& g) {
        const int kh = (k / 3) % 3, kw = k % 3;
        const float hs = (float)(h - 1 + kh) + dh;
        const float wsv = (float)(pw - 1 + kw) + dw;
        const float h0f = floorf(hs), w0f = floorf(wsv);
        const float fh = hs - h0f, fw = wsv - w0f;
        const int h0i = (int)h0f, w0i = (int)w0f;
        const int h1i = h0i + 1, w1i = w0i + 1;
        const float m_h0 = ((unsigned)h0i < H_) ? 1.f : 0.f;
        const float m_h1 = ((unsigned)h1i < H_) ? 1.f : 0.f;
        const float m_w0 = ((unsigned)w0i < W_) ? 1.f : 0.f;
        const float m_w1 = ((unsigned)w1i < W_) ? 1.f : 0.f;
        g.w00 = (1.f - fh) * (1.f - fw) * m_h0 * m_w0;
        g.w01 = (1.f - fh) * fw * m_h0 * m_w1;
        g.w10 = fh * (1.f - fw) * m_h1 * m_w0;
        g.w11 = fh * fw * m_h1 * m_w1;
        const int w0c = min(max(w0i, 0), W_ - 1);
        const int w1c = min(max(w1i, 0), W_ - 1);
        const int rh = h0i - (h - 2);
        if ((unsigned)rh <= 4u) {               // window path
            g.c[0] = rdwin(rh, w0c, ch);
            g.c[1] = rdwin(rh, w1c, ch);
            g.c[2] = rdwin(rh + 1, w0c, ch);
            g.c[3] = rdwin(rh + 1, w1c, ch);
        } else {                                 // rare fallback: global path
            const int h0c = min(max(h0i, 0), H_ - 1);
            const int h1c = min(max(h1i, 0), H_ - 1);
            const int tb = (t - 1 + k / 9) * HW_;
            g.c[0] = *(const bf16x8*)(y1b + (tb + h0c * W_ + w0c) * C_ + ch * 8);
            g.c[1] = *(const bf16x8*)(y1b + (tb + h0c * W_ + w1c) * C_ + ch * 8);
            g.c[2] = *(const bf16x8*)(y1b + (tb + h1c * W_ + w0c) * C_ + ch * 8);
            g.c[3] = *(const bf16x8*)(y1b + (tb + h1c * W_ + w1c) * C_ + ch * 8);
        }
    };
    auto blend1 = [&](const G1& g, bf16x8& fr) {
        union U { bf16x8 v; __hip_bfloat16 e[8]; };
        U c0, c1, c2, c3, r;
        c0.v = g.c[0]; c1.v = g.c[1]; c2.v = g.c[2]; c3.v = g.c[3];
#pragma unroll
        for (int j = 0; j < 8; ++j) {
            float f = g.w00 * __bfloat162float(c0.e[j]) + g.w01 * __bfloat162float(c1.e[j]) +
                      g.w10 * __bfloat162float(c2.e[j]) + g.w11 * __bfloat162float(c3.e[j]);
            r.e[j] = __float2bfloat16(f);
        }
        fr = r.v;
    };
    // B prefetch: loads issued one tap ahead, named regs (no dyn indexing)
    auto loadB = [&](int k, bf16x8& B0, bf16x8& B1, bf16x8& B2, bf16x8& B3) {
        const __hip_bfloat16* q = wds + k * 4096 + kh2 * 512 + lane * 8;
        B0 = *(const bf16x8*)(q);
        B1 = *(const bf16x8*)(q + 1024);
        B2 = *(const bf16x8*)(q + 2048);
        B3 = *(const bf16x8*)(q + 3072);
    };
    auto tapMFMA = [&](const bf16x8& fr, const bf16x8& B0, const bf16x8& B1,
                       const bf16x8& B2, const bf16x8& B3) {
        acc[0] = __builtin_amdgcn_mfma_f32_16x16x32_bf16(fr, B0, acc[0], 0, 0, 0);
        acc[1] = __builtin_amdgcn_mfma_f32_16x16x32_bf16(fr, B1, acc[1], 0, 0, 0);
        acc[2] = __builtin_amdgcn_mfma_f32_16x16x32_bf16(fr, B2, acc[2], 0, 0, 0);
        acc[3] = __builtin_amdgcn_mfma_f32_16x16x32_bf16(fr, B3, acc[3], 0, 0, 0);
    };

    G1 gA, gB;
    bf16x8 bA0, bA1, bA2, bA3, bB0, bB1, bB2, bB3;
#pragma unroll 1
    for (int kt = ktlo; kt < kthi; ++kt) {
        const int tin = t - 1 + kt;
        const int kg = kt * 9;

        LGKM_BARRIER();                 // prev group's window reads complete
        for (int i = tid; i < 6 * 64 * 8; i += 512) {
            const int rh = i >> 9;
            const int rem = i & 511;
            const int rw = rem >> 3;
            const int cc = rem & 7;
            const int hsrc = min(max(h - 2 + rh, 0), H_ - 1);
            const int u = (rh * 64 + rw) * 8 + (cc ^ (rw & 7));
            *(bf16x8*)((char*)win + u * 16) =
                *(const bf16x8*)&y1b[(tin * HW_ + hsrc * W_ + rw) * C_ + cc * 8];
        }
        LGKM_BARRIER();                 // window published

        {
            float dh, dw;
            load_off(kg, dh, dw);
            gatherW(kg, dh, dw, gA);
            loadB(kg, bA0, bA1, bA2, bA3);
        }
        int k = kg;
        for (; k + 1 < kg + 9; k += 2) {
            {   // tap k: prefetch gather+B for k+1, then blend+MFMA tap k
                float dh, dw;
                load_off(k + 1, dh, dw);
                gatherW(k + 1, dh, dw, gB);
                loadB(k + 1, bB0, bB1, bB2, bB3);
                bf16x8 fr;
                blend1(gA, fr);
                tapMFMA(fr, bA0, bA1, bA2, bA3);
            }
            {   // tap k+1: prefetch k+2, blend+MFMA k+1
                if (k + 2 < kg + 9) {
                    float dh, dw;
                    load_off(k + 2, dh, dw);
                    gatherW(k + 2, dh, dw, gA);
                    loadB(k + 2, bA0, bA1, bA2, bA3);
                }
                bf16x8 fr;
                blend1(gB, fr);
                tapMFMA(fr, bB0, bB1, bB2, bB3);
            }
        }
        {   // 9th tap (odd) — gA/bA valid
            bf16x8 fr;
            blend1(gA, fr);
            tapMFMA(fr, bA0, bA1, bA2, bA3);
        }
    }

    // ========== Final K-half reduction + epilogue ==========
    LGKM_BARRIER();                     // all window reads done -> win reusable
    if (kh2 == 1) {
#pragma unroll
        for (int g = 0; g < 4; ++g) {
            *(floatx4*)&winf[(pg * 64 + lane) * 32 + g * 4] = acc[g];
            *(floatx4*)&winf[(pg * 64 + lane) * 32 + 16 + g * 4] = racc[g];
        }
    }
    LGKM_BARRIER();
    if (kh2 == 0) {
#pragma unroll
        for (int g = 0; g < 4; ++g) {
            const floatx4 pa = *(const floatx4*)&winf[(pg * 64 + lane) * 32 + g * 4];
            const floatx4 pr = *(const floatx4*)&winf[(pg * 64 + lane) * 32 + 16 + g * 4];
            const int n = g * 16 + l15;
            const float bdv = bd[n], brv = br[n];
            floatx4 o;
#pragma unroll
            for (int r = 0; r < 4; ++r) {
                float v = acc[g][r] + pa[r] + bdv;
                v = (v >= 0.f) ? v : 0.01f * v;
                o[r] = v + racc[g][r] + pr[r] + brv;
            }
            *(floatx4*)&out[n * THW_ + posbase + pg * 16 + quad * 4] = o;
        }
    }
}

// ---------------------------------------------------------------------------
extern "C" void kernel_launch(void* const* d_in, const int* in_sizes, int n_in,
                              void* d_out, int out_size, void* d_ws, size_t ws_size,
                              hipStream_t stream) {
    const float* x    = (const float*)d_in[0];
    const float* W1   = (const float*)d_in[1];
    const float* b1   = (const float*)d_in[2];
    const float* Woff = (const float*)d_in[3];
    const float* boff = (const float*)d_in[4];
    const float* Wd   = (const float*)d_in[5];
    const float* bd   = (const float*)d_in[6];
    const float* Wr   = (const float*)d_in[7];
    const float* br   = (const float*)d_in[8];
    float* out = (float*)d_out;

    float* ws = (float*)d_ws;
    __hip_bfloat16* xclb  = (__hip_bfloat16*)(ws);             // 2,097,152 bf16
    __hip_bfloat16* y1b   = (__hip_bfloat16*)(ws + 1048576);   // 2,097,152 bf16
    __hip_bfloat16* w1s   = (__hip_bfloat16*)(ws + 2097152);   //   110,592 bf16
    __hip_bfloat16* woffs = (__hip_bfloat16*)(ws + 2152448);   //   110,592 bf16
    __hip_bfloat16* wdsb  = (__hip_bfloat16*)(ws + 2207744);   //   110,592 bf16
    __hip_bfloat16* wrsb  = (__hip_bfloat16*)(ws + 2263040);   //     4,096 bf16
    // total ~9.1 MB

    prep_tocl_kernel<<<THW_ / 64, 256, 0, stream>>>(
        x, xclb, W1, Woff, Wd, Wr, w1s, woffs, wdsb, wrsb);

    conv_stream_kernel<<<dim3(T_ * H_ * 2), 256, 0, stream>>>(
        xclb, w1s, b1, y1b);

    deform_fused_kernel<<<dim3(T_ * H_), 512, 0, stream>>>(
        y1b, woffs, boff, wdsb, bd, xclb, wrsb, br, out);
}

// Round 19
// 145.324 us; speedup vs baseline: 1.3164x; 1.0059x over previous
//
#include <hip/hip_runtime.h>
#include <hip/hip_bf16.h>

// Problem constants (B=1)
#define T_ 8
#define H_ 64
#define W_ 64
#define C_ 64
#define HW_ (H_ * W_)          // 4096
#define THW_ (T_ * H_ * W_)    // 32768
#define KTAPS 27
#define KDIM (C_ * KTAPS)      // 1728
#define NOFF 54
#define OSTR2 58               // offs LDS stride (floats)

typedef __bf16 bf16x8 __attribute__((ext_vector_type(8)));
typedef float floatx4 __attribute__((ext_vector_type(4)));

#define LGKM_BARRIER()                                        \
    do {                                                      \
        asm volatile("s_waitcnt lgkmcnt(0)" ::: "memory");    \
        __builtin_amdgcn_s_barrier();                         \
    } while (0)

// h-stripe XCD swizzle (R10-VERIFIED, kept).
#define DECODE_SWZ_CONV(bid, t, h, wh)                        \
    const int hi3_ = (bid) & 7;                               \
    const int rest_ = (bid) >> 3;                             \
    const int wh = rest_ & 1;                                 \
    const int h = hi3_ * 8 + ((rest_ >> 1) & 7);              \
    const int t = rest_ >> 4;
#define DECODE_SWZ_ROW(bid, t, h)                             \
    const int h = ((bid) & 7) * 8 + (((bid) >> 3) & 7);       \
    const int t = (bid) >> 6;

// ---------------------------------------------------------------------------
// prep + to_cl merged (unchanged).
// ---------------------------------------------------------------------------
__global__ __launch_bounds__(256) void prep_tocl_kernel(
    const float* __restrict__ x, __hip_bfloat16* __restrict__ xcl,
    const float* __restrict__ w1, const float* __restrict__ woff,
    const float* __restrict__ wd, const float* __restrict__ wr,
    __hip_bfloat16* __restrict__ w1s, __hip_bfloat16* __restrict__ woffs,
    __hip_bfloat16* __restrict__ wds, __hip_bfloat16* __restrict__ wrs) {
    __shared__ float tile[64][65];
    const int tid = threadIdx.x;

    {
        int i = blockIdx.x * 256 + tid;
        if (i < C_ * KDIM) {
            int j = i & 7, lane = (i >> 3) & 63, s = (i >> 9) & 1, g16 = (i >> 10) & 3, tap = i >> 12;
            int co = g16 * 16 + (lane & 15);
            int cin = s * 32 + (lane >> 4) * 8 + j;
            int src = (co * C_ + cin) * KTAPS + tap;
            w1s[i] = __float2bfloat16(w1[src]);
            woffs[i] = (co < NOFF) ? __float2bfloat16(woff[src]) : __float2bfloat16(0.f);
            wds[i] = __float2bfloat16(wd[src]);
        }
        if (i < C_ * C_) {
            int j = i & 7, lane = (i >> 3) & 63, s = (i >> 9) & 1, g16 = i >> 10;
            int co = g16 * 16 + (lane & 15);
            int cin = s * 32 + (lane >> 4) * 8 + j;
            wrs[i] = __float2bfloat16(wr[co * C_ + cin]);
        }
    }

    const int pos0 = blockIdx.x * 64;
    for (int i = tid; i < 4096; i += 256) {
        int ch = i >> 6, p = i & 63;
        tile[ch][p] = x[ch * THW_ + pos0 + p];
    }
    __syncthreads();
    for (int i = tid; i < 4096; i += 256) {
        int p = i >> 6, ch = i & 63;
        xcl[(pos0 + p) * C_ + ch] = __float2bfloat16(tile[ch][p]);
    }
}

// ---------------------------------------------------------------------------
// Streaming MFMA conv1 (R34): R14's A-window + the R18-VERIFIED tap-level
// software pipeline ported from deform. Each kt group = 9 uniform taps
// (invalid h rows ZERO-MASKED, not skipped -> branch-free pipeline; only
// h=0/63 blocks do 2 masked rows of extra MFMAs). 2-slot prefetch: tap k+1's
// 4 B-frags + 2 A window-reads issue while tap k's MFMAs run. First tap's
// B-prefetch issues BEFORE the window-publish barrier (VMEM rides across
// lgkm-only barriers, R1-verified).
// ---------------------------------------------------------------------------
__global__ __launch_bounds__(256) void conv_stream_kernel(
    const __hip_bfloat16* __restrict__ in_cl,
    const __hip_bfloat16* __restrict__ wTs,
    const float* __restrict__ bias,
    __hip_bfloat16* __restrict__ out_cl_b16) {
    __shared__ __hip_bfloat16 ts[32 * 72];            // 4608B bounce
    __shared__ __hip_bfloat16 awin[3 * 36 * C_];      // 13824B A-window (AWCP=36)

    const int tid = threadIdx.x;
    const int wv = tid >> 6;
    const int lane = tid & 63;
    const int l15 = lane & 15;
    const int quad = lane >> 4;
    DECODE_SWZ_CONV(blockIdx.x, t, h, wh)
    const int w0 = wh * 32;
    const int pg = wv >> 1;
    const int chf = wv & 1;
    const int wpos = w0 + pg * 16 + l15;
    const int posbase = t * HW_ + h * W_;

    floatx4 acc0 = (floatx4){0.f, 0.f, 0.f, 0.f};
    floatx4 acc1 = (floatx4){0.f, 0.f, 0.f, 0.f};
    const bf16x8 z = {};
    const __hip_bfloat16* wb = wTs + chf * 2048 + lane * 8;

    auto rdwin = [&](int rr, int cc, int chunk) -> bf16x8 {
        const int u = (rr * 36 + cc) * 8 + (chunk ^ (cc & 7));
        return *(const bf16x8*)((const char*)awin + u * 16);
    };
    // prefetch slot fill: tap k (0..8) of group kt
    auto fetch = [&](int kt, int k, bf16x8& a0, bf16x8& a1,
                     bf16x8& B0, bf16x8& B1, bf16x8& B2, bf16x8& B3) {
        const int kh = k / 3, kw = k % 3;
        const __hip_bfloat16* bp = wb + (kt * 9 + k) * 4096;
        B0 = *(const bf16x8*)(bp);
        B1 = *(const bf16x8*)(bp + 512);
        B2 = *(const bf16x8*)(bp + 1024);
        B3 = *(const bf16x8*)(bp + 1536);
        const int rw = pg * 16 + l15 + kw;    // 0..34, always in-window
        a0 = rdwin(kh, rw, quad);
        a1 = rdwin(kh, rw, quad + 4);
    };
    auto compute = [&](int k, bf16x8 a0, bf16x8 a1, const bf16x8& B0,
                       const bf16x8& B1, const bf16x8& B2, const bf16x8& B3) {
        const int kh = k / 3, kw = k % 3;
        const int h_in = h - 1 + kh;
        const int w_in = wpos - 1 + kw;
        const bool v = ((unsigned)h_in < H_) && ((unsigned)w_in < W_);
        a0 = v ? a0 : z;
        a1 = v ? a1 : z;
        acc0 = __builtin_amdgcn_mfma_f32_16x16x32_bf16(a0, B0, acc0, 0, 0, 0);
        acc0 = __builtin_amdgcn_mfma_f32_16x16x32_bf16(a1, B1, acc0, 0, 0, 0);
        acc1 = __builtin_amdgcn_mfma_f32_16x16x32_bf16(a0, B2, acc1, 0, 0, 0);
        acc1 = __builtin_amdgcn_mfma_f32_16x16x32_bf16(a1, B3, acc1, 0, 0, 0);
    };

    const int ktlo = (t == 0) ? 1 : 0;
    const int kthi = (t == T_ - 1) ? 2 : 3;

#pragma unroll 1
    for (int kt = ktlo; kt < kthi; ++kt) {
        const int t_in = t - 1 + kt;

        LGKM_BARRIER();                 // prev kt window reads complete
        for (int i = tid; i < 3 * 35 * 8; i += 256) {
            const int rh = i / (35 * 8);
            const int rem = i - rh * (35 * 8);
            const int rw = rem >> 3;
            const int cc = rem & 7;
            const int hsrc = min(max(h - 1 + rh, 0), H_ - 1);
            const int wsrc = min(max(w0 - 1 + rw, 0), W_ - 1);
            const int u = (rh * 36 + rw) * 8 + (cc ^ (rw & 7));
            *(bf16x8*)((char*)awin + u * 16) =
                *(const bf16x8*)&in_cl[(t_in * HW_ + hsrc * W_ + wsrc) * C_ + cc * 8];
        }
        // first tap's B-prefetch rides across the publish barrier (VMEM)
        bf16x8 sAa0, sAa1, sAb0, sAb1, sAb2, sAb3;
        bf16x8 sBa0, sBa1, sBb0, sBb1, sBb2, sBb3;
        {
            const __hip_bfloat16* bp = wb + (kt * 9) * 4096;
            sAb0 = *(const bf16x8*)(bp);
            sAb1 = *(const bf16x8*)(bp + 512);
            sAb2 = *(const bf16x8*)(bp + 1024);
            sAb3 = *(const bf16x8*)(bp + 1536);
        }
        LGKM_BARRIER();                 // window published
        {   // A-reads for tap 0 (post-barrier)
            const int rw = pg * 16 + l15;    // kw=0
            sAa0 = rdwin(0, rw, quad);
            sAa1 = rdwin(0, rw, quad + 4);
        }

        int k = 0;
        for (; k + 1 < 9; k += 2) {
            fetch(kt, k + 1, sBa0, sBa1, sBb0, sBb1, sBb2, sBb3);
            compute(k, sAa0, sAa1, sAb0, sAb1, sAb2, sAb3);
            if (k + 2 < 9) fetch(kt, k + 2, sAa0, sAa1, sAb0, sAb1, sAb2, sAb3);
            compute(k + 1, sBa0, sBa1, sBb0, sBb1, sBb2, sBb3);
        }
        compute(8, sAa0, sAa1, sAb0, sAb1, sAb2, sAb3);   // 9th tap (slot A)
    }

    const int n0 = chf * 32 + l15;
    const float bv0 = bias[n0], bv1 = bias[n0 + 16];
#pragma unroll
    for (int r = 0; r < 4; ++r) {
        const int p = pg * 16 + quad * 4 + r;
        float v0 = acc0[r] + bv0;
        v0 = (v0 >= 0.f) ? v0 : 0.01f * v0;
        float v1 = acc1[r] + bv1;
        v1 = (v1 >= 0.f) ? v1 : 0.01f * v1;
        ts[p * 72 + n0] = __float2bfloat16(v0);
        ts[p * 72 + n0 + 16] = __float2bfloat16(v1);
    }
    __syncthreads();
    {
        const int p = tid >> 3, ck = tid & 7;
        const uint4 v4 = *(const uint4*)&ts[p * 72 + ck * 8];
        *(uint4*)&out_cl_b16[(posbase + w0 + p) * C_ + ck * 8] = v4;
    }
}

// ---------------------------------------------------------------------------
// FUSED offsets-conv + deform + residual (R34): R18 structure (K-split +
// B-prefetch, verified 56.2us) with the window shrunk 6 -> 5 rows
// (h-2..h+2; R13-verified semantics: window-hit check rh<=3, |dh|>=1 lanes
// take the global fallback). -1/6 staging traffic; LDS 64000 -> 55808.
// ---------------------------------------------------------------------------
struct G1 {
    bf16x8 c[4];          // 4 corners, my K-half chunk only
    float w00, w01, w10, w11;
};

__global__ __launch_bounds__(512, 4) void deform_fused_kernel(
    const __hip_bfloat16* __restrict__ y1b,
    const __hip_bfloat16* __restrict__ woffs, const float* __restrict__ boff,
    const __hip_bfloat16* __restrict__ wds, const float* __restrict__ bd,
    const __hip_bfloat16* __restrict__ xclb, const __hip_bfloat16* __restrict__ wrs,
    const float* __restrict__ br, float* __restrict__ out) {
    __shared__ __hip_bfloat16 win[5 * 64 * 64];   // 40960 B (window + red buf)
    __shared__ float offs[4][16][OSTR2];          // 14848 B

    const int tid = threadIdx.x;
    const int wv = tid >> 6;
    const int lane = tid & 63;
    const int l15 = lane & 15;
    const int quad = lane >> 4;
    DECODE_SWZ_ROW(blockIdx.x, t, h)
    const int posbase = t * HW_ + h * W_;
    const int pg = wv & 3;               // position group (16 pos)
    const int kh2 = wv >> 2;             // K half (input channels kh2*32..)
    const int pw = pg * 16 + l15;        // this lane's position (w coord)
    const int ch = quad + kh2 * 4;       // my K-chunk index (0..7)

    const int ktlo = (t == 0) ? 1 : 0;
    const int kthi = (t == T_ - 1) ? 2 : 3;

    float* winf = (float*)win;

    auto rdwin = [&](int rr, int cc, int chunk) -> bf16x8 {
        const int u = (rr * 64 + cc) * 8 + (chunk ^ (cc & 7));
        return *(const bf16x8*)((const char*)win + u * 16);
    };

    // ========== Loop A: phase 1 (offsets conv), K-split, 3-row window ======
    {
        floatx4 oacc[4];
#pragma unroll
        for (int g = 0; g < 4; ++g) oacc[g] = (floatx4){0.f, 0.f, 0.f, 0.f};
        const bf16x8 z = {};

#pragma unroll 1
        for (int kt = ktlo; kt < kthi; ++kt) {
            const int tin = t - 1 + kt;

            LGKM_BARRIER();             // prev window reads complete
            for (int i = tid; i < 3 * 64 * 8; i += 512) {
                const int rh = i >> 9;
                const int rem = i & 511;
                const int rw = rem >> 3;
                const int cc = rem & 7;
                const int hsrc = min(max(h - 1 + rh, 0), H_ - 1);
                const int u = (rh * 64 + rw) * 8 + (cc ^ (rw & 7));
                *(bf16x8*)((char*)win + u * 16) =
                    *(const bf16x8*)&y1b[(tin * HW_ + hsrc * W_ + rw) * C_ + cc * 8];
            }
            LGKM_BARRIER();             // window published

#pragma unroll 1
            for (int kh = 0; kh < 3; ++kh) {
                const int h_in = h - 1 + kh;
                if ((unsigned)h_in >= H_) continue;
#pragma unroll
                for (int kw = 0; kw < 3; ++kw) {
                    const int tap = kt * 9 + kh * 3 + kw;
                    const int w_in = pw - 1 + kw;
                    const bool v = (unsigned)w_in < W_;
                    const int wc = v ? w_in : 0;
                    bf16x8 a = rdwin(kh, wc, ch);
                    a = v ? a : z;
                    const __hip_bfloat16* op = woffs + tap * 4096 + kh2 * 512 + lane * 8;
#pragma unroll
                    for (int g = 0; g < 4; ++g) {
                        const bf16x8 b = *(const bf16x8*)(op + g * 1024);
                        oacc[g] = __builtin_amdgcn_mfma_f32_16x16x32_bf16(a, b, oacc[g], 0, 0, 0);
                    }
                }
            }
        }
        // K-half reduction (identical layouts, elementwise)
        LGKM_BARRIER();                 // all window reads done -> win reusable
        if (kh2 == 1) {
#pragma unroll
            for (int g = 0; g < 4; ++g)
                *(floatx4*)&winf[(pg * 64 + lane) * 16 + g * 4] = oacc[g];
        }
        LGKM_BARRIER();
        if (kh2 == 0) {
#pragma unroll
            for (int g = 0; g < 4; ++g) {
                const floatx4 p4 = *(const floatx4*)&winf[(pg * 64 + lane) * 16 + g * 4];
                oacc[g] += p4;
                const int idx = g * 16 + l15;
                if (idx < NOFF) {
                    const float bo = boff[idx];
#pragma unroll
                    for (int r = 0; r < 4; ++r)
                        offs[pg][quad * 4 + r][idx] = oacc[g][r] + bo;
                }
            }
        }
    }
    // offs + win handoff published at loop B's first LGKM_BARRIER

    // ========== Loop B: phase 2 (window gather, K-split) + residual ========
    floatx4 acc[4], racc[4];
#pragma unroll
    for (int g = 0; g < 4; ++g) {
        acc[g] = (floatx4){0.f, 0.f, 0.f, 0.f};
        racc[g] = (floatx4){0.f, 0.f, 0.f, 0.f};
    }

    // residual 1x1 conv, K-half partial
    {
        const bf16x8 ra = *(const bf16x8*)(xclb + (posbase + pw) * C_ + ch * 8);
        const __hip_bfloat16* q = wrs + kh2 * 512 + lane * 8;
#pragma unroll
        for (int g = 0; g < 4; ++g) {
            const bf16x8 r0 = *(const bf16x8*)(q + g * 1024);
            racc[g] = __builtin_amdgcn_mfma_f32_16x16x32_bf16(ra, r0, racc[g], 0, 0, 0);
        }
    }

    auto load_off = [&](int k, float& dh, float& dw) {
        dh = offs[pg][l15][2 * k];
        dw = offs[pg][l15][2 * k + 1];
    };
    auto gatherW = [&](int k, float dh, float dw, G1& g) {
        const int kh = (k / 3) % 3, kw = k % 3;
        const float hs = (float)(h - 1 + kh) + dh;
        const float wsv = (float)(pw - 1 + kw) + dw;
        const float h0f = floorf(hs), w0f = floorf(wsv);
        const float fh = hs - h0f, fw = wsv - w0f;
        const int h0i = (int)h0f, w0i = (int)w0f;
        const int h1i = h0i + 1, w1i = w0i + 1;
        const float m_h0 = ((unsigned)h0i < H_) ? 1.f : 0.f;
        const float m_h1 = ((unsigned)h1i < H_) ? 1.f : 0.f;
        const float m_w0 = ((unsigned)w0i < W_) ? 1.f : 0.f;
        const float m_w1 = ((unsigned)w1i < W_) ? 1.f : 0.f;
        g.w00 = (1.f - fh) * (1.f - fw) * m_h0 * m_w0;
        g.w01 = (1.f - fh) * fw * m_h0 * m_w1;
        g.w10 = fh * (1.f - fw) * m_h1 * m_w0;
        g.w11 = fh * fw * m_h1 * m_w1;
        const int w0c = min(max(w0i, 0), W_ - 1);
        const int w1c = min(max(w1i, 0), W_ - 1);
        const int rh = h0i - (h - 2);
        if ((unsigned)rh <= 3u) {               // 5-row window path (R13-verified)
            g.c[0] = rdwin(rh, w0c, ch);
            g.c[1] = rdwin(rh, w1c, ch);
            g.c[2] = rdwin(rh + 1, w0c, ch);
            g.c[3] = rdwin(rh + 1, w1c, ch);
        } else {                                 // rare fallback: global path
            const int h0c = min(max(h0i, 0), H_ - 1);
            const int h1c = min(max(h1i, 0), H_ - 1);
            const int tb = (t - 1 + k / 9) * HW_;
            g.c[0] = *(const bf16x8*)(y1b + (tb + h0c * W_ + w0c) * C_ + ch * 8);
            g.c[1] = *(const bf16x8*)(y1b + (tb + h0c * W_ + w1c) * C_ + ch * 8);
            g.c[2] = *(const bf16x8*)(y1b + (tb + h1c * W_ + w0c) * C_ + ch * 8);
            g.c[3] = *(const bf16x8*)(y1b + (tb + h1c * W_ + w1c) * C_ + ch * 8);
        }
    };
    auto blend1 = [&](const G1& g, bf16x8& fr) {
        union U { bf16x8 v; __hip_bfloat16 e[8]; };
        U c0, c1, c2, c3, r;
        c0.v = g.c[0]; c1.v = g.c[1]; c2.v = g.c[2]; c3.v = g.c[3];
#pragma unroll
        for (int j = 0; j < 8; ++j) {
            float f = g.w00 * __bfloat162float(c0.e[j]) + g.w01 * __bfloat162float(c1.e[j]) +
                      g.w10 * __bfloat162float(c2.e[j]) + g.w11 * __bfloat162float(c3.e[j]);
            r.e[j] = __float2bfloat16(f);
        }
        fr = r.v;
    };
    auto loadB = [&](int k, bf16x8& B0, bf16x8& B1, bf16x8& B2, bf16x8& B3) {
        const __hip_bfloat16* q = wds + k * 4096 + kh2 * 512 + lane * 8;
        B0 = *(const bf16x8*)(q);
        B1 = *(const bf16x8*)(q + 1024);
        B2 = *(const bf16x8*)(q + 2048);
        B3 = *(const bf16x8*)(q + 3072);
    };
    auto tapMFMA = [&](const bf16x8& fr, const bf16x8& B0, const bf16x8& B1,
                       const bf16x8& B2, const bf16x8& B3) {
        acc[0] = __builtin_amdgcn_mfma_f32_16x16x32_bf16(fr, B0, acc[0], 0, 0, 0);
        acc[1] = __builtin_amdgcn_mfma_f32_16x16x32_bf16(fr, B1, acc[1], 0, 0, 0);
        acc[2] = __builtin_amdgcn_mfma_f32_16x16x32_bf16(fr, B2, acc[2], 0, 0, 0);
        acc[3] = __builtin_amdgcn_mfma_f32_16x16x32_bf16(fr, B3, acc[3], 0, 0, 0);
    };

    G1 gA, gB;
    bf16x8 bA0, bA1, bA2, bA3, bB0, bB1, bB2, bB3;
#pragma unroll 1
    for (int kt = ktlo; kt < kthi; ++kt) {
        const int tin = t - 1 + kt;
        const int kg = kt * 9;

        LGKM_BARRIER();                 // prev group's window reads complete
        for (int i = tid; i < 5 * 64 * 8; i += 512) {
            const int rh = i >> 9;
            const int rem = i & 511;
            const int rw = rem >> 3;
            const int cc = rem & 7;
            const int hsrc = min(max(h - 2 + rh, 0), H_ - 1);
            const int u = (rh * 64 + rw) * 8 + (cc ^ (rw & 7));
            *(bf16x8*)((char*)win + u * 16) =
                *(const bf16x8*)&y1b[(tin * HW_ + hsrc * W_ + rw) * C_ + cc * 8];
        }
        LGKM_BARRIER();                 // window published

        {
            float dh, dw;
            load_off(kg, dh, dw);
            gatherW(kg, dh, dw, gA);
            loadB(kg, bA0, bA1, bA2, bA3);
        }
        int k = kg;
        for (; k + 1 < kg + 9; k += 2) {
            {   // tap k: prefetch gather+B for k+1, then blend+MFMA tap k
                float dh, dw;
                load_off(k + 1, dh, dw);
                gatherW(k + 1, dh, dw, gB);
                loadB(k + 1, bB0, bB1, bB2, bB3);
                bf16x8 fr;
                blend1(gA, fr);
                tapMFMA(fr, bA0, bA1, bA2, bA3);
            }
            {   // tap k+1: prefetch k+2, blend+MFMA k+1
                if (k + 2 < kg + 9) {
                    float dh, dw;
                    load_off(k + 2, dh, dw);
                    gatherW(k + 2, dh, dw, gA);
                    loadB(k + 2, bA0, bA1, bA2, bA3);
                }
                bf16x8 fr;
                blend1(gB, fr);
                tapMFMA(fr, bB0, bB1, bB2, bB3);
            }
        }
        {   // 9th tap (odd) — gA/bA valid
            bf16x8 fr;
            blend1(gA, fr);
            tapMFMA(fr, bA0, bA1, bA2, bA3);
        }
    }

    // ========== Final K-half reduction + epilogue ==========
    LGKM_BARRIER();                     // all window reads done -> win reusable
    if (kh2 == 1) {
#pragma unroll
        for (int g = 0; g < 4; ++g) {
            *(floatx4*)&winf[(pg * 64 + lane) * 32 + g * 4] = acc[g];
            *(floatx4*)&winf[(pg * 64 + lane) * 32 + 16 + g * 4] = racc[g];
        }
    }
    LGKM_BARRIER();
    if (kh2 == 0) {
#pragma unroll
        for (int g = 0; g < 4; ++g) {
            const floatx4 pa = *(const floatx4*)&winf[(pg * 64 + lane) * 32 + g * 4];
            const floatx4 pr = *(const floatx4*)&winf[(pg * 64 + lane) * 32 + 16 + g * 4];
            const int n = g * 16 + l15;
            const float bdv = bd[n], brv = br[n];
            floatx4 o;
#pragma unroll
            for (int r = 0; r < 4; ++r) {
                float v = acc[g][r] + pa[r] + bdv;
                v = (v >= 0.f) ? v : 0.01f * v;
                o[r] = v + racc[g][r] + pr[r] + brv;
            }
            *(floatx4*)&out[n * THW_ + posbase + pg * 16 + quad * 4] = o;
        }
    }
}

// ---------------------------------------------------------------------------
extern "C" void kernel_launch(void* const* d_in, const int* in_sizes, int n_in,
                              void* d_out, int out_size, void* d_ws, size_t ws_size,
                              hipStream_t stream) {
    const float* x    = (const float*)d_in[0];
    const float* W1   = (const float*)d_in[1];
    const float* b1   = (const float*)d_in[2];
    const float* Woff = (const float*)d_in[3];
    const float* boff = (const float*)d_in[4];
    const float* Wd   = (const float*)d_in[5];
    const float* bd   = (const float*)d_in[6];
    const float* Wr   = (const float*)d_in[7];
    const float* br   = (const float*)d_in[8];
    float* out = (float*)d_out;

    float* ws = (float*)d_ws;
    __hip_bfloat16* xclb  = (__hip_bfloat16*)(ws);             // 2,097,152 bf16
    __hip_bfloat16* y1b   = (__hip_bfloat16*)(ws + 1048576);   // 2,097,152 bf16
    __hip_bfloat16* w1s   = (__hip_bfloat16*)(ws + 2097152);   //   110,592 bf16
    __hip_bfloat16* woffs = (__hip_bfloat16*)(ws + 2152448);   //   110,592 bf16
    __hip_bfloat16* wdsb  = (__hip_bfloat16*)(ws + 2207744);   //   110,592 bf16
    __hip_bfloat16* wrsb  = (__hip_bfloat16*)(ws + 2263040);   //     4,096 bf16
    // total ~9.1 MB

    prep_tocl_kernel<<<THW_ / 64, 256, 0, stream>>>(
        x, xclb, W1, Woff, Wd, Wr, w1s, woffs, wdsb, wrsb);

    conv_stream_kernel<<<dim3(T_ * H_ * 2), 256, 0, stream>>>(
        xclb, w1s, b1, y1b);

    deform_fused_kernel<<<dim3(T_ * H_), 512, 0, stream>>>(
        y1b, woffs, boff, wdsb, bd, xclb, wrsb, br, out);
}